// Round 5
// baseline (406.175 us; speedup 1.0000x reference)
//
#include <hip/hip_runtime.h>
#include <math.h>

#define DEV __device__ __forceinline__
DEV float leakyf(float v) { return v >= 0.f ? v : 0.01f * v; }
DEV int rfl(int v) { return __builtin_amdgcn_readfirstlane(v); }

// ---- ws layout (float offsets) ----
#define OFF_A    0u          // h1  [64][8][64][64]   2097152
#define OFF_B    2097152u    // h2  [64][16][32][32]  1048576
#define OFF_C    3145728u    // h3  [64][16][32][32]  1048576
#define OFF_D1   4194304u    // d1  [64][16][32][32]  1048576
#define OFF_D2   5242880u    // dt2 [64][8][64][64]   2097152
#define OFF_IDX  7340032u    // 65536 int32
#define OFF_W1T  7405568u    // 128   [tap16][co8]
#define OFF_W2T  7405696u    // 2048  [cg4][ci8][tap16][co4]
#define OFF_W3T  7407744u    // 2304  [cg4][ci16][tap9][co4]
#define OFF_W4T  7410048u    // 1024  [ci16][d64]
#define OFF_WT2T 7411072u    // 2048  [cg2][ci16][tap16][co4]
#define OFF_C2   7413120u    // 512
#define OFF_U    7413632u    // 73728 [k512][tap9][co16]
#define OFF_LOSS 7487360u    // 1 (+pad)
#define OFF_DWT  7487488u    // 9216  [ci64][tap9*16+co16]

// ---------- prep: weight transposes + |c|^2 ----------
__global__ void prep_k(const float* __restrict__ ew1, const float* __restrict__ ew2,
                       const float* __restrict__ ew3, const float* __restrict__ ew4,
                       const float* __restrict__ dw1, const float* __restrict__ dw2,
                       const float* __restrict__ cb, float* __restrict__ ws)
{
    int b = blockIdx.x, t = threadIdx.x;
    if (b < 8) {                      // W2T: [((cg*8+ci)*16+tap)*4+cj] = ew2[co][ci][tap]
        int id = b * 256 + t;
        int cj = id & 3, tap = (id >> 2) & 15, ci = (id >> 6) & 7, cg = id >> 9;
        ws[OFF_W2T + id] = ew2[(((cg * 4 + cj) * 8) + ci) * 16 + tap];
    } else if (b < 17) {              // W3T: [((cg*16+ci)*9+tap)*4+cj]
        int id = (b - 8) * 256 + t;
        if (id < 2304) {
            int cj = id & 3, r = id >> 2;
            int tap = r % 9, ci = (r / 9) & 15, cg = r / 144;
            ws[OFF_W3T + id] = ew3[(((cg * 4 + cj) * 16) + ci) * 9 + tap];
        }
    } else if (b < 21) {              // W4T: [ci*64+d] = ew4[d][ci]
        int id = (b - 17) * 256 + t;
        int d = id & 63, ci = id >> 6;
        ws[OFF_W4T + id] = ew4[d * 16 + ci];
    } else if (b < 29) {              // WT2T: [((cg*16+ci)*16+tap)*4+cj] = dw2[ci][co][tap]
        int id = (b - 21) * 256 + t;
        int cj = id & 3, tap = (id >> 2) & 15, ci = (id >> 6) & 15, cg = id >> 10;
        ws[OFF_WT2T + id] = dw2[((ci * 8) + cg * 4 + cj) * 16 + tap];
    } else if (b == 29) {             // W1T: [tap*8+co] = ew1[co][tap]
        if (t < 128) {
            int co = t & 7, tap = t >> 3;
            ws[OFF_W1T + t] = ew1[co * 16 + tap];
        }
    } else if (b < 32) {              // C2
        int k = (b - 30) * 256 + t;
        float s = 0.f;
        #pragma unroll
        for (int d = 0; d < 64; ++d) { float v = cb[k * 64 + d]; s = fmaf(v, v, s); }
        ws[OFF_C2 + k] = s;
    } else {                          // DWT: [ci*144 + tap*16 + co] = dw1[co][ci][tap]
        int id = (b - 32) * 256 + t;
        if (id < 9216) {
            int co = id & 15, tap = (id >> 4) % 9, ci = id / 144;
            ws[OFF_DWT + id] = dw1[(co * 64 + ci) * 9 + tap];
        }
    }
}

// U[k][tap][co] = sum_ci dwT[ci][tap*16+co] * cb[k][ci]   (coalesced)
__global__ void uprep_k(const float* __restrict__ dwT, const float* __restrict__ cb,
                        float* __restrict__ U)
{
    int id = blockIdx.x * 256 + threadIdx.x;   // 73728 = k*144 + (tap*16+co)
    int k = id / 144;
    int r = id - k * 144;
    float s = 0.f;
    #pragma unroll
    for (int ci = 0; ci < 64; ++ci)
        s = fmaf(cb[k * 64 + ci], dwT[ci * 144 + r], s);
    U[id] = s;
}

// ---------- encoder ----------
__global__ __launch_bounds__(256) void e1_k(const float* __restrict__ x,
                                            const float* __restrict__ w1t,
                                            const float* __restrict__ eb1,
                                            float* __restrict__ out)
{
    int id = blockIdx.x * 256 + threadIdx.x;          // 262144
    int px = id & 63, py = (id >> 6) & 63, n = id >> 12;
    float acc[8];
    #pragma unroll
    for (int j = 0; j < 8; ++j) acc[j] = eb1[j];
    const float4* w4p = (const float4*)w1t;
    const float* ip = x + (n << 14);
    #pragma unroll
    for (int ky = 0; ky < 4; ++ky) {
        int iy = 2 * py - 1 + ky;
        bool vy = iy >= 0 && iy < 128;
        #pragma unroll
        for (int kx = 0; kx < 4; ++kx) {
            int ix = 2 * px - 1 + kx;
            float v = (vy && ix >= 0 && ix < 128) ? ip[(iy << 7) + ix] : 0.f;
            float4 wa = w4p[(ky * 4 + kx) * 2], wb = w4p[(ky * 4 + kx) * 2 + 1];
            acc[0] = fmaf(v, wa.x, acc[0]); acc[1] = fmaf(v, wa.y, acc[1]);
            acc[2] = fmaf(v, wa.z, acc[2]); acc[3] = fmaf(v, wa.w, acc[3]);
            acc[4] = fmaf(v, wb.x, acc[4]); acc[5] = fmaf(v, wb.y, acc[5]);
            acc[6] = fmaf(v, wb.z, acc[6]); acc[7] = fmaf(v, wb.w, acc[7]);
        }
    }
    #pragma unroll
    for (int j = 0; j < 8; ++j)
        out[((n * 8 + j) << 12) + (py << 6) + px] = leakyf(acc[j]);
}

__global__ __launch_bounds__(256) void e2_k(const float* __restrict__ in,
                                            const float* __restrict__ w2t,
                                            const float* __restrict__ eb2,
                                            float* __restrict__ out)
{
    int id = blockIdx.x * 256 + threadIdx.x;          // 262144
    int x = id & 31, y = (id >> 5) & 31;
    int cg = rfl((id >> 10) & 3), n = id >> 12;
    float acc[4];
    #pragma unroll
    for (int j = 0; j < 4; ++j) acc[j] = eb2[cg * 4 + j];
    const float4* w4p = (const float4*)w2t;
    #pragma unroll
    for (int ci = 0; ci < 8; ++ci) {
        const float* ip = in + ((n * 8 + ci) << 12);
        #pragma unroll
        for (int ky = 0; ky < 4; ++ky) {
            int iy = 2 * y - 1 + ky;
            bool vy = iy >= 0 && iy < 64;
            #pragma unroll
            for (int kx = 0; kx < 4; ++kx) {
                int ix = 2 * x - 1 + kx;
                float v = (vy && ix >= 0 && ix < 64) ? ip[(iy << 6) + ix] : 0.f;
                float4 wv = w4p[(cg * 8 + ci) * 16 + ky * 4 + kx];
                acc[0] = fmaf(v, wv.x, acc[0]); acc[1] = fmaf(v, wv.y, acc[1]);
                acc[2] = fmaf(v, wv.z, acc[2]); acc[3] = fmaf(v, wv.w, acc[3]);
            }
        }
    }
    #pragma unroll
    for (int j = 0; j < 4; ++j)
        out[((n * 16 + cg * 4 + j) << 10) + (y << 5) + x] = leakyf(acc[j]);
}

__global__ __launch_bounds__(256) void e3_k(const float* __restrict__ in,
                                            const float* __restrict__ w3t,
                                            const float* __restrict__ eb3,
                                            float* __restrict__ out)
{
    int id = blockIdx.x * 256 + threadIdx.x;          // 262144
    int x = id & 31, y = (id >> 5) & 31;
    int cg = rfl((id >> 10) & 3), n = id >> 12;
    float acc[4];
    #pragma unroll
    for (int j = 0; j < 4; ++j) acc[j] = eb3[cg * 4 + j];
    const float4* w4p = (const float4*)w3t;
    #pragma unroll
    for (int ci = 0; ci < 16; ++ci) {
        const float* ip = in + ((n * 16 + ci) << 10);
        #pragma unroll
        for (int tap = 0; tap < 9; ++tap) {
            int iy = y + tap / 3 - 1, ix = x + tap % 3 - 1;
            float v = (iy >= 0 && iy < 32 && ix >= 0 && ix < 32) ? ip[(iy << 5) + ix] : 0.f;
            float4 wv = w4p[(cg * 16 + ci) * 9 + tap];
            acc[0] = fmaf(v, wv.x, acc[0]); acc[1] = fmaf(v, wv.y, acc[1]);
            acc[2] = fmaf(v, wv.z, acc[2]); acc[3] = fmaf(v, wv.w, acc[3]);
        }
    }
    #pragma unroll
    for (int j = 0; j < 4; ++j)
        out[((n * 16 + cg * 4 + j) << 10) + (y << 5) + x] = leakyf(acc[j]);
}

// ---------- fused e4 (1x1 conv) + VQ argmin + loss, outputs indices ----------
// waves_per_eu(4,4): pin the allocator's occupancy target to 4 waves/EU
// (128-VGPR budget) so f[64] + a[4][4] stay in registers — defeats the
// perf-hint pass that otherwise targets 8 waves (64 VGPR) and spills f[].
__global__ __launch_bounds__(256)
__attribute__((amdgpu_waves_per_eu(4, 4)))
void vq3_k(const float* __restrict__ h3,
           const float* __restrict__ cb,
           const float* __restrict__ w4t,
           const float* __restrict__ c2,
           const float* __restrict__ eb4,
           int* __restrict__ idxOut,
           float* __restrict__ lossAcc)
{
    __shared__ float sS[256];
    __shared__ int   sI[256];
    int t = threadIdx.x, lane = t & 63;
    int w = rfl(t >> 6);
    int m = blockIdx.x * 64 + lane;
    int n = m >> 10, pos = m & 1023;

    // e4: f = leaky(W4 h3 + b4), SGPR-streamed weights
    const float* hp = h3 + (n << 14) + pos;
    float h[16];
    #pragma unroll
    for (int ci = 0; ci < 16; ++ci) h[ci] = hp[ci << 10];
    float f[64];
    #pragma unroll
    for (int d = 0; d < 64; ++d) f[d] = eb4[d];
    #pragma unroll
    for (int ci = 0; ci < 16; ++ci) {
        float v = h[ci];
        #pragma unroll
        for (int d = 0; d < 64; ++d) f[d] = fmaf(v, w4t[ci * 64 + d], f[d]);
    }
    #pragma unroll
    for (int d = 0; d < 64; ++d) f[d] = leakyf(f[d]);

    // this wave scans codes [w*128, w*128+128), 4 codes per iter
    const float4* cb4 = (const float4*)cb;
    int k0 = w << 7;
    float best = 3.4e38f; int bk = 0;
    #pragma unroll 1
    for (int kk = 0; kk < 128; kk += 4) {
        int ka = k0 + kk;
        float a[4][4] = {};
        #pragma unroll
        for (int q = 0; q < 16; ++q) {
            float f0 = f[q * 4 + 0], f1 = f[q * 4 + 1];
            float f2 = f[q * 4 + 2], f3 = f[q * 4 + 3];
            #pragma unroll
            for (int c = 0; c < 4; ++c) {
                float4 cv = cb4[(ka + c) * 16 + q];
                a[c][0] = fmaf(f0, cv.x, a[c][0]);
                a[c][1] = fmaf(f1, cv.y, a[c][1]);
                a[c][2] = fmaf(f2, cv.z, a[c][2]);
                a[c][3] = fmaf(f3, cv.w, a[c][3]);
            }
        }
        #pragma unroll
        for (int c = 0; c < 4; ++c) {
            float s = fmaf(0.5f, c2[ka + c], -((a[c][0] + a[c][1]) + (a[c][2] + a[c][3])));
            if (s < best) { best = s; bk = ka + c; }
        }
    }
    sS[t] = best; sI[t] = bk;
    __syncthreads();
    if (t < 64) {
        float bs = sS[t]; int bi = sI[t];
        #pragma unroll
        for (int ww = 1; ww < 4; ++ww) {       // ascending k ranges: strict < keeps first min
            float s2 = sS[ww * 64 + t];
            int   i2 = sI[ww * 64 + t];
            if (s2 < bs) { bs = s2; bi = i2; }
        }
        idxOut[blockIdx.x * 64 + t] = bi;
        // loss: sum (cb[bi] - f)^2  (commitment == embedding in fwd)
        float rs = 0.f;
        #pragma unroll
        for (int q = 0; q < 16; ++q) {
            float4 c = cb4[bi * 16 + q];
            float d0 = c.x - f[q * 4 + 0], d1 = c.y - f[q * 4 + 1];
            float d2 = c.z - f[q * 4 + 2], d3 = c.w - f[q * 4 + 3];
            rs = fmaf(d0, d0, rs); rs = fmaf(d1, d1, rs);
            rs = fmaf(d2, d2, rs); rs = fmaf(d3, d3, rs);
        }
        #pragma unroll
        for (int off = 32; off; off >>= 1) rs += __shfl_down(rs, off, 64);
        if (t == 0) atomicAdd(lossAcc, rs);
    }
}

// ---------- decoder conv1 via U-table (co-split 4, 1024 blocks) ----------
__global__ __launch_bounds__(256) void d1_k(const int* __restrict__ idx,
                                            const float* __restrict__ U,
                                            const float* __restrict__ db1,
                                            float* __restrict__ out)
{
    int id = blockIdx.x * 256 + threadIdx.x;          // 262144
    int x = id & 31, y = (id >> 5) & 31;
    int cg = rfl((id >> 10) & 3), n = id >> 12;
    float acc[4];
    #pragma unroll
    for (int j = 0; j < 4; ++j) acc[j] = db1[cg * 4 + j];
    const float4* U4 = (const float4*)U;
    #pragma unroll
    for (int tap = 0; tap < 9; ++tap) {
        int yy = y + tap / 3 - 1, xx = x + tap % 3 - 1;
        if (yy < 0 || yy > 31 || xx < 0 || xx > 31) continue;
        int k = idx[(n << 10) + (yy << 5) + xx];
        float4 u = U4[(k * 9 + tap) * 4 + cg];
        acc[0] += u.x; acc[1] += u.y; acc[2] += u.z; acc[3] += u.w;
    }
    #pragma unroll
    for (int j = 0; j < 4; ++j)
        out[((n * 16 + cg * 4 + j) << 10) + (y << 5) + x] = leakyf(acc[j]);
}

// ---------- ConvT 16->8, K4 S2 P1, parity-block form ----------
__global__ __launch_bounds__(256) void dt2_k(const float* __restrict__ in,
                                             const float* __restrict__ wt,
                                             const float* __restrict__ db2,
                                             float* __restrict__ out)
{
    int id = blockIdx.x * 256 + threadIdx.x;          // 131072
    int x = id & 31, y = (id >> 5) & 31;
    int cg = rfl((id >> 10) & 1), n = id >> 11;
    float acc[2][2][4];
    #pragma unroll
    for (int py = 0; py < 2; ++py)
        #pragma unroll
        for (int px = 0; px < 2; ++px)
            #pragma unroll
            for (int j = 0; j < 4; ++j) acc[py][px][j] = db2[cg * 4 + j];
    const float4* wt4 = (const float4*)wt;
    #pragma unroll
    for (int ci = 0; ci < 16; ++ci) {
        const float* ip = in + ((n * 16 + ci) << 10);
        float v[3][3];
        #pragma unroll
        for (int dy = -1; dy <= 1; ++dy)
            #pragma unroll
            for (int dx = -1; dx <= 1; ++dx) {
                int yy = y + dy, xx = x + dx;
                v[dy + 1][dx + 1] = (yy >= 0 && yy < 32 && xx >= 0 && xx < 32)
                                        ? ip[(yy << 5) + xx] : 0.f;
            }
        #pragma unroll
        for (int ky = 0; ky < 4; ++ky) {
            int py = (ky + 1) & 1;
            int dy = (ky == 0) ? 1 : (ky == 3 ? -1 : 0);
            #pragma unroll
            for (int kx = 0; kx < 4; ++kx) {
                int px = (kx + 1) & 1;
                int dx = (kx == 0) ? 1 : (kx == 3 ? -1 : 0);
                float4 wv = wt4[(cg * 16 + ci) * 16 + ky * 4 + kx];
                float vv = v[dy + 1][dx + 1];
                acc[py][px][0] = fmaf(vv, wv.x, acc[py][px][0]);
                acc[py][px][1] = fmaf(vv, wv.y, acc[py][px][1]);
                acc[py][px][2] = fmaf(vv, wv.z, acc[py][px][2]);
                acc[py][px][3] = fmaf(vv, wv.w, acc[py][px][3]);
            }
        }
    }
    #pragma unroll
    for (int py = 0; py < 2; ++py)
        #pragma unroll
        for (int px = 0; px < 2; ++px)
            #pragma unroll
            for (int j = 0; j < 4; ++j)
                out[((n * 8 + cg * 4 + j) << 12) + ((2 * y + py) << 6) + 2 * x + px] =
                    leakyf(acc[py][px][j]);
}

// ---------- ConvT 8->1, K4 S2 P1, tanh ----------
__global__ __launch_bounds__(256) void dt3_k(const float* __restrict__ in,
                                             const float* __restrict__ dw3,
                                             const float* __restrict__ db3,
                                             float* __restrict__ out)
{
    int id = blockIdx.x * 256 + threadIdx.x;          // 262144
    int x = id & 63, y = (id >> 6) & 63, n = id >> 12;
    float b = db3[0];
    float acc[2][2] = {{b, b}, {b, b}};
    #pragma unroll
    for (int ci = 0; ci < 8; ++ci) {
        const float* ip = in + ((n * 8 + ci) << 12);
        float v[3][3];
        #pragma unroll
        for (int dy = -1; dy <= 1; ++dy)
            #pragma unroll
            for (int dx = -1; dx <= 1; ++dx) {
                int yy = y + dy, xx = x + dx;
                v[dy + 1][dx + 1] = (yy >= 0 && yy < 64 && xx >= 0 && xx < 64)
                                        ? ip[(yy << 6) + xx] : 0.f;
            }
        #pragma unroll
        for (int ky = 0; ky < 4; ++ky) {
            int py = (ky + 1) & 1;
            int dy = (ky == 0) ? 1 : (ky == 3 ? -1 : 0);
            #pragma unroll
            for (int kx = 0; kx < 4; ++kx) {
                int px = (kx + 1) & 1;
                int dx = (kx == 0) ? 1 : (kx == 3 ? -1 : 0);
                acc[py][px] = fmaf(v[dy + 1][dx + 1], dw3[ci * 16 + ky * 4 + kx], acc[py][px]);
            }
        }
    }
    #pragma unroll
    for (int py = 0; py < 2; ++py)
        #pragma unroll
        for (int px = 0; px < 2; ++px)
            out[(n << 14) + ((2 * y + py) << 7) + 2 * x + px] = tanhf(acc[py][px]);
}

__global__ void loss_k(const float* __restrict__ acc, float* __restrict__ out)
{
    out[0] = 1.25f * acc[0] / 4194304.0f;
}

extern "C" void kernel_launch(void* const* d_in, const int* in_sizes, int n_in,
                              void* d_out, int out_size, void* d_ws, size_t ws_size,
                              hipStream_t stream)
{
    const float* x        = (const float*)d_in[0];
    const float* ew1      = (const float*)d_in[1];
    const float* eb1      = (const float*)d_in[2];
    const float* ew2      = (const float*)d_in[3];
    const float* eb2      = (const float*)d_in[4];
    const float* ew3      = (const float*)d_in[5];
    const float* eb3      = (const float*)d_in[6];
    const float* ew4      = (const float*)d_in[7];
    const float* eb4      = (const float*)d_in[8];
    const float* codebook = (const float*)d_in[9];
    const float* dw1      = (const float*)d_in[10];
    const float* db1      = (const float*)d_in[11];
    const float* dw2      = (const float*)d_in[12];
    const float* db2      = (const float*)d_in[13];
    const float* dw3      = (const float*)d_in[14];
    const float* db3      = (const float*)d_in[15];

    float* out = (float*)d_out;
    float* ws  = (float*)d_ws;
    float* A    = ws + OFF_A;
    float* B    = ws + OFF_B;
    float* C    = ws + OFF_C;
    float* D1   = ws + OFF_D1;
    float* D2   = ws + OFF_D2;
    int*   IDX  = (int*)(ws + OFF_IDX);
    float* W1T  = ws + OFF_W1T;
    float* W2T  = ws + OFF_W2T;
    float* W3T  = ws + OFF_W3T;
    float* W4T  = ws + OFF_W4T;
    float* WT2T = ws + OFF_WT2T;
    float* C2   = ws + OFF_C2;
    float* U    = ws + OFF_U;
    float* LOSS = ws + OFF_LOSS;
    float* DWT  = ws + OFF_DWT;

    hipMemsetAsync(LOSS, 0, sizeof(float), stream);
    prep_k<<<68, 256, 0, stream>>>(ew1, ew2, ew3, ew4, dw1, dw2, codebook, ws);
    uprep_k<<<288, 256, 0, stream>>>(DWT, codebook, U);

    e1_k<<<1024, 256, 0, stream>>>(x, W1T, eb1, A);
    e2_k<<<1024, 256, 0, stream>>>(A, W2T, eb2, B);
    e3_k<<<1024, 256, 0, stream>>>(B, W3T, eb3, C);

    vq3_k<<<1024, 256, 0, stream>>>(C, codebook, W4T, C2, eb4, IDX, LOSS);

    d1_k<<<1024, 256, 0, stream>>>(IDX, U, db1, D1);
    dt2_k<<<512, 256, 0, stream>>>(D1, WT2T, db2, D2);
    dt3_k<<<1024, 256, 0, stream>>>(D2, dw3, db3, out);

    loss_k<<<1, 1, 0, stream>>>(LOSS, out + 1048576);
}

// Round 6
// 284.836 us; speedup vs baseline: 1.4260x; 1.4260x over previous
//
#include <hip/hip_runtime.h>
#include <math.h>

#define DEV __device__ __forceinline__
DEV float leakyf(float v) { return v >= 0.f ? v : 0.01f * v; }
DEV int rfl(int v) { return __builtin_amdgcn_readfirstlane(v); }

// ---- ws layout (float offsets) ----
#define OFF_A    0u          // h1  [64][8][64][64]   2097152
#define OFF_B    2097152u    // h2  [64][16][32][32]  1048576
#define OFF_C    3145728u    // h3  [64][16][32][32]  1048576
#define OFF_D1   4194304u    // d1  [64][16][32][32]  1048576
#define OFF_D2   5242880u    // dt2 [64][8][64][64]   2097152
#define OFF_IDX  7340032u    // 65536 int32
#define OFF_W1T  7405568u    // 128   [tap16][co8]
#define OFF_W2T  7405696u    // 2048  [cg4][ci8][tap16][co4]
#define OFF_W3T  7407744u    // 2304  [cg4][ci16][tap9][co4]
#define OFF_W4T  7410048u    // 1024  [ci16][d64]
#define OFF_WT2T 7411072u    // 2048  [cg2][ci16][tap16][co4]
#define OFF_C2   7413120u    // 512
#define OFF_U    7413632u    // 73728 [k512][tap9][co16]
#define OFF_LOSS 7487360u    // 1 (+pad)
#define OFF_DWT  7487488u    // 9216  [ci64][tap9*16+co16]
#define OFF_CTG  7496704u    // 32768 [k/8][d64][8] code stream

// ---------- prep: weight transposes + |c|^2 + code stream ----------
__global__ void prep_k(const float* __restrict__ ew1, const float* __restrict__ ew2,
                       const float* __restrict__ ew3, const float* __restrict__ ew4,
                       const float* __restrict__ dw1, const float* __restrict__ dw2,
                       const float* __restrict__ cb, float* __restrict__ ws)
{
    int b = blockIdx.x, t = threadIdx.x;
    if (b < 8) {                      // W2T: [((cg*8+ci)*16+tap)*4+cj] = ew2[co][ci][tap]
        int id = b * 256 + t;
        int cj = id & 3, tap = (id >> 2) & 15, ci = (id >> 6) & 7, cg = id >> 9;
        ws[OFF_W2T + id] = ew2[(((cg * 4 + cj) * 8) + ci) * 16 + tap];
    } else if (b < 17) {              // W3T: [((cg*16+ci)*9+tap)*4+cj]
        int id = (b - 8) * 256 + t;
        if (id < 2304) {
            int cj = id & 3, r = id >> 2;
            int tap = r % 9, ci = (r / 9) & 15, cg = r / 144;
            ws[OFF_W3T + id] = ew3[(((cg * 4 + cj) * 16) + ci) * 9 + tap];
        }
    } else if (b < 21) {              // W4T: [ci*64+d] = ew4[d][ci]
        int id = (b - 17) * 256 + t;
        int d = id & 63, ci = id >> 6;
        ws[OFF_W4T + id] = ew4[d * 16 + ci];
    } else if (b < 29) {              // WT2T: [((cg*16+ci)*16+tap)*4+cj] = dw2[ci][co][tap]
        int id = (b - 21) * 256 + t;
        int cj = id & 3, tap = (id >> 2) & 15, ci = (id >> 6) & 15, cg = id >> 10;
        ws[OFF_WT2T + id] = dw2[((ci * 8) + cg * 4 + cj) * 16 + tap];
    } else if (b == 29) {             // W1T: [tap*8+co] = ew1[co][tap]
        if (t < 128) {
            int co = t & 7, tap = t >> 3;
            ws[OFF_W1T + t] = ew1[co * 16 + tap];
        }
    } else if (b < 32) {              // C2
        int k = (b - 30) * 256 + t;
        float s = 0.f;
        #pragma unroll
        for (int d = 0; d < 64; ++d) { float v = cb[k * 64 + d]; s = fmaf(v, v, s); }
        ws[OFF_C2 + k] = s;
    } else if (b < 68) {              // DWT: [ci*144 + tap*16 + co] = dw1[co][ci][tap]
        int id = (b - 32) * 256 + t;
        if (id < 9216) {
            int co = id & 15, tap = (id >> 4) % 9, ci = id / 144;
            ws[OFF_DWT + id] = dw1[(co * 64 + ci) * 9 + tap];
        }
    } else {                          // CTG: [g*512 + d*8 + j] = cb[(g*8+j)*64 + d]
        int id = (b - 68) * 256 + t;  // 32768
        int j = id & 7, d = (id >> 3) & 63, g = id >> 9;
        ws[OFF_CTG + id] = cb[((g * 8 + j) << 6) + d];
    }
}

// U[k][tap][co] = sum_ci dwT[ci][tap*16+co] * cb[k][ci]   (coalesced)
__global__ void uprep_k(const float* __restrict__ dwT, const float* __restrict__ cb,
                        float* __restrict__ U)
{
    int id = blockIdx.x * 256 + threadIdx.x;   // 73728 = k*144 + (tap*16+co)
    int k = id / 144;
    int r = id - k * 144;
    float s = 0.f;
    #pragma unroll
    for (int ci = 0; ci < 64; ++ci)
        s = fmaf(cb[k * 64 + ci], dwT[ci * 144 + r], s);
    U[id] = s;
}

// ---------- encoder ----------
__global__ __launch_bounds__(256) void e1_k(const float* __restrict__ x,
                                            const float* __restrict__ w1t,
                                            const float* __restrict__ eb1,
                                            float* __restrict__ out)
{
    int id = blockIdx.x * 256 + threadIdx.x;          // 262144
    int px = id & 63, py = (id >> 6) & 63, n = id >> 12;
    float acc[8];
    #pragma unroll
    for (int j = 0; j < 8; ++j) acc[j] = eb1[j];
    const float4* w4p = (const float4*)w1t;
    const float* ip = x + (n << 14);
    #pragma unroll
    for (int ky = 0; ky < 4; ++ky) {
        int iy = 2 * py - 1 + ky;
        bool vy = iy >= 0 && iy < 128;
        #pragma unroll
        for (int kx = 0; kx < 4; ++kx) {
            int ix = 2 * px - 1 + kx;
            float v = (vy && ix >= 0 && ix < 128) ? ip[(iy << 7) + ix] : 0.f;
            float4 wa = w4p[(ky * 4 + kx) * 2], wb = w4p[(ky * 4 + kx) * 2 + 1];
            acc[0] = fmaf(v, wa.x, acc[0]); acc[1] = fmaf(v, wa.y, acc[1]);
            acc[2] = fmaf(v, wa.z, acc[2]); acc[3] = fmaf(v, wa.w, acc[3]);
            acc[4] = fmaf(v, wb.x, acc[4]); acc[5] = fmaf(v, wb.y, acc[5]);
            acc[6] = fmaf(v, wb.z, acc[6]); acc[7] = fmaf(v, wb.w, acc[7]);
        }
    }
    #pragma unroll
    for (int j = 0; j < 8; ++j)
        out[((n * 8 + j) << 12) + (py << 6) + px] = leakyf(acc[j]);
}

__global__ __launch_bounds__(256) void e2_k(const float* __restrict__ in,
                                            const float* __restrict__ w2t,
                                            const float* __restrict__ eb2,
                                            float* __restrict__ out)
{
    int id = blockIdx.x * 256 + threadIdx.x;          // 262144
    int x = id & 31, y = (id >> 5) & 31;
    int cg = rfl((id >> 10) & 3), n = id >> 12;
    float acc[4];
    #pragma unroll
    for (int j = 0; j < 4; ++j) acc[j] = eb2[cg * 4 + j];
    const float4* w4p = (const float4*)w2t;
    #pragma unroll
    for (int ci = 0; ci < 8; ++ci) {
        const float* ip = in + ((n * 8 + ci) << 12);
        #pragma unroll
        for (int ky = 0; ky < 4; ++ky) {
            int iy = 2 * y - 1 + ky;
            bool vy = iy >= 0 && iy < 64;
            #pragma unroll
            for (int kx = 0; kx < 4; ++kx) {
                int ix = 2 * x - 1 + kx;
                float v = (vy && ix >= 0 && ix < 64) ? ip[(iy << 6) + ix] : 0.f;
                float4 wv = w4p[(cg * 8 + ci) * 16 + ky * 4 + kx];
                acc[0] = fmaf(v, wv.x, acc[0]); acc[1] = fmaf(v, wv.y, acc[1]);
                acc[2] = fmaf(v, wv.z, acc[2]); acc[3] = fmaf(v, wv.w, acc[3]);
            }
        }
    }
    #pragma unroll
    for (int j = 0; j < 4; ++j)
        out[((n * 16 + cg * 4 + j) << 10) + (y << 5) + x] = leakyf(acc[j]);
}

__global__ __launch_bounds__(256) void e3_k(const float* __restrict__ in,
                                            const float* __restrict__ w3t,
                                            const float* __restrict__ eb3,
                                            float* __restrict__ out)
{
    int id = blockIdx.x * 256 + threadIdx.x;          // 262144
    int x = id & 31, y = (id >> 5) & 31;
    int cg = rfl((id >> 10) & 3), n = id >> 12;
    float acc[4];
    #pragma unroll
    for (int j = 0; j < 4; ++j) acc[j] = eb3[cg * 4 + j];
    const float4* w4p = (const float4*)w3t;
    #pragma unroll
    for (int ci = 0; ci < 16; ++ci) {
        const float* ip = in + ((n * 16 + ci) << 10);
        #pragma unroll
        for (int tap = 0; tap < 9; ++tap) {
            int iy = y + tap / 3 - 1, ix = x + tap % 3 - 1;
            float v = (iy >= 0 && iy < 32 && ix >= 0 && ix < 32) ? ip[(iy << 5) + ix] : 0.f;
            float4 wv = w4p[(cg * 16 + ci) * 9 + tap];
            acc[0] = fmaf(v, wv.x, acc[0]); acc[1] = fmaf(v, wv.y, acc[1]);
            acc[2] = fmaf(v, wv.z, acc[2]); acc[3] = fmaf(v, wv.w, acc[3]);
        }
    }
    #pragma unroll
    for (int j = 0; j < 4; ++j)
        out[((n * 16 + cg * 4 + j) << 10) + (y << 5) + x] = leakyf(acc[j]);
}

// ---------- fused e4 + VQ: 128 rows/block staged in LDS, SGPR code stream ----
// Per lane: 2 rows x 8 codes => 16 fma per ds_read_b64. acc/regs ~40 VGPR:
// fits the 8-wave (64 VGPR) budget with zero spill by construction.
__global__ __launch_bounds__(512) void vqf_k(const float* __restrict__ h3,
                                             const float* __restrict__ w4t,
                                             const float* __restrict__ eb4,
                                             const float* __restrict__ ctG,
                                             const float* __restrict__ c2,
                                             const float* __restrict__ cb,
                                             int* __restrict__ idxOut,
                                             float* __restrict__ lossAcc)
{
    __shared__ float Fs[64 * 128];     // [d][r]  32 KB
    __shared__ float redS[8 * 128];    // 4 KB
    __shared__ int   redI[8 * 128];    // 4 KB
    int t = threadIdx.x;
    int b = blockIdx.x;                // 512 blocks
    int n = b >> 3, pos0 = (b & 7) << 7;

    // ---- stage: e4 (1x1 conv) for 128 rows, d-chunked so regs stay ~40 ----
    if (t < 128) {
        int r = t;
        const float* hp = h3 + (n << 14) + pos0 + r;
        float h[16];
        #pragma unroll
        for (int ci = 0; ci < 16; ++ci) h[ci] = hp[ci << 10];
        #pragma unroll
        for (int dc = 0; dc < 4; ++dc) {
            float a[16];
            #pragma unroll
            for (int j = 0; j < 16; ++j) a[j] = eb4[dc * 16 + j];
            #pragma unroll
            for (int ci = 0; ci < 16; ++ci) {
                float v = h[ci];
                #pragma unroll
                for (int j = 0; j < 16; ++j)
                    a[j] = fmaf(v, w4t[ci * 64 + dc * 16 + j], a[j]);
            }
            #pragma unroll
            for (int j = 0; j < 16; ++j)
                Fs[(dc * 16 + j) * 128 + r] = leakyf(a[j]);
        }
    }
    __syncthreads();

    // ---- scan: wave w covers codes [w*64,(w+1)*64), lane owns rows 2l,2l+1 --
    int lane = t & 63;
    int w = rfl(t >> 6);
    const float2* Fs2 = (const float2*)Fs;
    float best0 = 3.4e38f, best1 = 3.4e38f;
    int bk0 = 0, bk1 = 0;
    #pragma unroll 1
    for (int cg = 0; cg < 8; ++cg) {
        int k0 = (w << 6) + (cg << 3);         // uniform
        const float* cp = ctG + (k0 << 6);     // contiguous 2KB stream per cg
        float acc[2][8] = {};
        #pragma unroll 8
        for (int d = 0; d < 64; ++d) {
            float2 fv = Fs2[(d << 6) + lane];
            #pragma unroll
            for (int j = 0; j < 8; ++j) {
                float cv = cp[(d << 3) + j];   // uniform -> s_load
                acc[0][j] = fmaf(fv.x, cv, acc[0][j]);
                acc[1][j] = fmaf(fv.y, cv, acc[1][j]);
            }
        }
        #pragma unroll
        for (int j = 0; j < 8; ++j) {
            float hc2 = 0.5f * c2[k0 + j];
            float s0 = hc2 - acc[0][j];
            float s1 = hc2 - acc[1][j];
            if (s0 < best0) { best0 = s0; bk0 = k0 + j; }
            if (s1 < best1) { best1 = s1; bk1 = k0 + j; }
        }
    }
    redS[(w << 7) + lane * 2 + 0] = best0;
    redS[(w << 7) + lane * 2 + 1] = best1;
    redI[(w << 7) + lane * 2 + 0] = bk0;
    redI[(w << 7) + lane * 2 + 1] = bk1;
    __syncthreads();

    // ---- final reduce (ascending wave = ascending k range, strict <) -------
    if (t < 128) {
        int r = t;
        float bs = redS[r]; int bi = redI[r];
        #pragma unroll
        for (int ww = 1; ww < 8; ++ww) {
            float s = redS[(ww << 7) + r];
            int  ii = redI[(ww << 7) + r];
            if (s < bs) { bs = s; bi = ii; }
        }
        idxOut[(n << 10) + pos0 + r] = bi;
        // loss: sum (cb[bi] - f)^2  (commitment == embedding in fwd)
        float rs = 0.f;
        const float4* cr4 = (const float4*)(cb + (bi << 6));
        #pragma unroll
        for (int q = 0; q < 16; ++q) {
            float4 c = cr4[q];
            float e0 = c.x - Fs[((q << 2) + 0) * 128 + r];
            float e1 = c.y - Fs[((q << 2) + 1) * 128 + r];
            float e2 = c.z - Fs[((q << 2) + 2) * 128 + r];
            float e3 = c.w - Fs[((q << 2) + 3) * 128 + r];
            rs = fmaf(e0, e0, rs); rs = fmaf(e1, e1, rs);
            rs = fmaf(e2, e2, rs); rs = fmaf(e3, e3, rs);
        }
        #pragma unroll
        for (int off = 32; off; off >>= 1) rs += __shfl_down(rs, off, 64);
        if ((t & 63) == 0) atomicAdd(lossAcc, rs);
    }
}

// ---------- decoder conv1 via U-table (co-split 4, 1024 blocks) ----------
__global__ __launch_bounds__(256) void d1_k(const int* __restrict__ idx,
                                            const float* __restrict__ U,
                                            const float* __restrict__ db1,
                                            float* __restrict__ out)
{
    int id = blockIdx.x * 256 + threadIdx.x;          // 262144
    int x = id & 31, y = (id >> 5) & 31;
    int cg = rfl((id >> 10) & 3), n = id >> 12;
    float acc[4];
    #pragma unroll
    for (int j = 0; j < 4; ++j) acc[j] = db1[cg * 4 + j];
    const float4* U4 = (const float4*)U;
    #pragma unroll
    for (int tap = 0; tap < 9; ++tap) {
        int yy = y + tap / 3 - 1, xx = x + tap % 3 - 1;
        if (yy < 0 || yy > 31 || xx < 0 || xx > 31) continue;
        int k = idx[(n << 10) + (yy << 5) + xx];
        float4 u = U4[(k * 9 + tap) * 4 + cg];
        acc[0] += u.x; acc[1] += u.y; acc[2] += u.z; acc[3] += u.w;
    }
    #pragma unroll
    for (int j = 0; j < 4; ++j)
        out[((n * 16 + cg * 4 + j) << 10) + (y << 5) + x] = leakyf(acc[j]);
}

// ---------- ConvT 16->8, K4 S2 P1, parity-block form ----------
__global__ __launch_bounds__(256) void dt2_k(const float* __restrict__ in,
                                             const float* __restrict__ wt,
                                             const float* __restrict__ db2,
                                             float* __restrict__ out)
{
    int id = blockIdx.x * 256 + threadIdx.x;          // 131072
    int x = id & 31, y = (id >> 5) & 31;
    int cg = rfl((id >> 10) & 1), n = id >> 11;
    float acc[2][2][4];
    #pragma unroll
    for (int py = 0; py < 2; ++py)
        #pragma unroll
        for (int px = 0; px < 2; ++px)
            #pragma unroll
            for (int j = 0; j < 4; ++j) acc[py][px][j] = db2[cg * 4 + j];
    const float4* wt4 = (const float4*)wt;
    #pragma unroll
    for (int ci = 0; ci < 16; ++ci) {
        const float* ip = in + ((n * 16 + ci) << 10);
        float v[3][3];
        #pragma unroll
        for (int dy = -1; dy <= 1; ++dy)
            #pragma unroll
            for (int dx = -1; dx <= 1; ++dx) {
                int yy = y + dy, xx = x + dx;
                v[dy + 1][dx + 1] = (yy >= 0 && yy < 32 && xx >= 0 && xx < 32)
                                        ? ip[(yy << 5) + xx] : 0.f;
            }
        #pragma unroll
        for (int ky = 0; ky < 4; ++ky) {
            int py = (ky + 1) & 1;
            int dy = (ky == 0) ? 1 : (ky == 3 ? -1 : 0);
            #pragma unroll
            for (int kx = 0; kx < 4; ++kx) {
                int px = (kx + 1) & 1;
                int dx = (kx == 0) ? 1 : (kx == 3 ? -1 : 0);
                float4 wv = wt4[(cg * 16 + ci) * 16 + ky * 4 + kx];
                float vv = v[dy + 1][dx + 1];
                acc[py][px][0] = fmaf(vv, wv.x, acc[py][px][0]);
                acc[py][px][1] = fmaf(vv, wv.y, acc[py][px][1]);
                acc[py][px][2] = fmaf(vv, wv.z, acc[py][px][2]);
                acc[py][px][3] = fmaf(vv, wv.w, acc[py][px][3]);
            }
        }
    }
    #pragma unroll
    for (int py = 0; py < 2; ++py)
        #pragma unroll
        for (int px = 0; px < 2; ++px)
            #pragma unroll
            for (int j = 0; j < 4; ++j)
                out[((n * 8 + cg * 4 + j) << 12) + ((2 * y + py) << 6) + 2 * x + px] =
                    leakyf(acc[py][px][j]);
}

// ---------- ConvT 8->1, K4 S2 P1, tanh ----------
__global__ __launch_bounds__(256) void dt3_k(const float* __restrict__ in,
                                             const float* __restrict__ dw3,
                                             const float* __restrict__ db3,
                                             float* __restrict__ out)
{
    int id = blockIdx.x * 256 + threadIdx.x;          // 262144
    int x = id & 63, y = (id >> 6) & 63, n = id >> 12;
    float b = db3[0];
    float acc[2][2] = {{b, b}, {b, b}};
    #pragma unroll
    for (int ci = 0; ci < 8; ++ci) {
        const float* ip = in + ((n * 8 + ci) << 12);
        float v[3][3];
        #pragma unroll
        for (int dy = -1; dy <= 1; ++dy)
            #pragma unroll
            for (int dx = -1; dx <= 1; ++dx) {
                int yy = y + dy, xx = x + dx;
                v[dy + 1][dx + 1] = (yy >= 0 && yy < 64 && xx >= 0 && xx < 64)
                                        ? ip[(yy << 6) + xx] : 0.f;
            }
        #pragma unroll
        for (int ky = 0; ky < 4; ++ky) {
            int py = (ky + 1) & 1;
            int dy = (ky == 0) ? 1 : (ky == 3 ? -1 : 0);
            #pragma unroll
            for (int kx = 0; kx < 4; ++kx) {
                int px = (kx + 1) & 1;
                int dx = (kx == 0) ? 1 : (kx == 3 ? -1 : 0);
                acc[py][px] = fmaf(v[dy + 1][dx + 1], dw3[ci * 16 + ky * 4 + kx], acc[py][px]);
            }
        }
    }
    #pragma unroll
    for (int py = 0; py < 2; ++py)
        #pragma unroll
        for (int px = 0; px < 2; ++px)
            out[(n << 14) + ((2 * y + py) << 7) + 2 * x + px] = tanhf(acc[py][px]);
}

__global__ void loss_k(const float* __restrict__ acc, float* __restrict__ out)
{
    out[0] = 1.25f * acc[0] / 4194304.0f;
}

extern "C" void kernel_launch(void* const* d_in, const int* in_sizes, int n_in,
                              void* d_out, int out_size, void* d_ws, size_t ws_size,
                              hipStream_t stream)
{
    const float* x        = (const float*)d_in[0];
    const float* ew1      = (const float*)d_in[1];
    const float* eb1      = (const float*)d_in[2];
    const float* ew2      = (const float*)d_in[3];
    const float* eb2      = (const float*)d_in[4];
    const float* ew3      = (const float*)d_in[5];
    const float* eb3      = (const float*)d_in[6];
    const float* ew4      = (const float*)d_in[7];
    const float* eb4      = (const float*)d_in[8];
    const float* codebook = (const float*)d_in[9];
    const float* dw1      = (const float*)d_in[10];
    const float* db1      = (const float*)d_in[11];
    const float* dw2      = (const float*)d_in[12];
    const float* db2      = (const float*)d_in[13];
    const float* dw3      = (const float*)d_in[14];
    const float* db3      = (const float*)d_in[15];

    float* out = (float*)d_out;
    float* ws  = (float*)d_ws;
    float* A    = ws + OFF_A;
    float* B    = ws + OFF_B;
    float* C    = ws + OFF_C;
    float* D1   = ws + OFF_D1;
    float* D2   = ws + OFF_D2;
    int*   IDX  = (int*)(ws + OFF_IDX);
    float* W1T  = ws + OFF_W1T;
    float* W2T  = ws + OFF_W2T;
    float* W3T  = ws + OFF_W3T;
    float* W4T  = ws + OFF_W4T;
    float* WT2T = ws + OFF_WT2T;
    float* C2   = ws + OFF_C2;
    float* U    = ws + OFF_U;
    float* LOSS = ws + OFF_LOSS;
    float* DWT  = ws + OFF_DWT;
    float* CTG  = ws + OFF_CTG;

    hipMemsetAsync(LOSS, 0, sizeof(float), stream);
    prep_k<<<196, 256, 0, stream>>>(ew1, ew2, ew3, ew4, dw1, dw2, codebook, ws);
    uprep_k<<<288, 256, 0, stream>>>(DWT, codebook, U);

    e1_k<<<1024, 256, 0, stream>>>(x, W1T, eb1, A);
    e2_k<<<1024, 256, 0, stream>>>(A, W2T, eb2, B);
    e3_k<<<1024, 256, 0, stream>>>(B, W3T, eb3, C);

    vqf_k<<<512, 512, 0, stream>>>(C, W4T, eb4, CTG, C2, codebook, IDX, LOSS);

    d1_k<<<1024, 256, 0, stream>>>(IDX, U, db1, D1);
    dt2_k<<<512, 256, 0, stream>>>(D1, WT2T, db2, D2);
    dt3_k<<<1024, 256, 0, stream>>>(D2, dw3, db3, out);

    loss_k<<<1, 1, 0, stream>>>(LOSS, out + 1048576);
}

// Round 7
// 273.665 us; speedup vs baseline: 1.4842x; 1.0408x over previous
//
#include <hip/hip_runtime.h>
#include <math.h>

#define DEV __device__ __forceinline__
DEV float leakyf(float v) { return v >= 0.f ? v : 0.01f * v; }
DEV int rfl(int v) { return __builtin_amdgcn_readfirstlane(v); }

// ---- ws layout (float offsets) ----
#define OFF_A    0u          // h1  [64][8][64][64]   2097152
#define OFF_B    2097152u    // h2  [64][16][32][32]  1048576
#define OFF_C    3145728u    // h3  [64][16][32][32]  1048576
#define OFF_F    4194304u    // F   [65536][64]       4194304
#define OFF_D1   8388608u    // d1  [64][16][32][32]  1048576
#define OFF_D2   9437184u    // dt2 [64][8][64][64]   2097152
#define OFF_IDX  11534336u   // 65536 int32
#define OFF_U    11599872u   // 73728 [k512][tap9][co16]
#define OFF_C2   11673600u   // 512
#define OFF_W4T  11674112u   // 1024 [ci16][d64]
#define OFF_DWT  11675136u   // 9216 [ci64][tap9*16+co16]
#define OFF_LOSS 11684352u   // 1

// ---------- prep: W4T transpose, |c|^2, dw1 transpose ----------
__global__ void prep_k(const float* __restrict__ ew4, const float* __restrict__ dw1,
                       const float* __restrict__ cb, float* __restrict__ ws)
{
    int b = blockIdx.x, t = threadIdx.x;
    if (b < 4) {                      // W4T: [ci*64+d] = ew4[d][ci]
        int id = b * 256 + t;
        int d = id & 63, ci = id >> 6;
        ws[OFF_W4T + id] = ew4[d * 16 + ci];
    } else if (b < 6) {               // C2
        int k = (b - 4) * 256 + t;
        float s = 0.f;
        #pragma unroll
        for (int d = 0; d < 64; ++d) { float v = cb[k * 64 + d]; s = fmaf(v, v, s); }
        ws[OFF_C2 + k] = s;
    } else {                          // DWT: [ci*144 + tap*16 + co] = dw1[co][ci][tap]
        int id = (b - 6) * 256 + t;
        if (id < 9216) {
            int co = id & 15, tap = (id >> 4) % 9, ci = id / 144;
            ws[OFF_DWT + id] = dw1[(co * 64 + ci) * 9 + tap];
        }
    }
}

// U[k][tap][co] = sum_ci dwT[ci][tap*16+co] * cb[k][ci]
__global__ void uprep_k(const float* __restrict__ dwT, const float* __restrict__ cb,
                        float* __restrict__ U)
{
    int id = blockIdx.x * 256 + threadIdx.x;   // 73728 = k*144 + (tap*16+co)
    int k = id / 144;
    int r = id - k * 144;
    float s = 0.f;
    #pragma unroll
    for (int ci = 0; ci < 64; ++ci)
        s = fmaf(cb[k * 64 + ci], dwT[ci * 144 + r], s);
    U[id] = s;
}

// ---------- forward conv (round-2 proven): thread = spatial pos, COB chans ---
template<int CIN, int COUT, int COB, int K, int S, int P, int HIN, int HOUT>
__global__ __launch_bounds__(256) void convf_k(const float* __restrict__ in,
                                               const float* __restrict__ w,
                                               const float* __restrict__ b,
                                               float* __restrict__ out)
{
    constexpr int NCG = COUT / COB;
    constexpr int WSZ = CIN * K * K * COB;
    __shared__ float wl[WSZ];
    int t = threadIdx.x;
    int idx = blockIdx.x * 256 + t;
    int x  = idx % HOUT;
    int y  = (idx / HOUT) % HOUT;
    int cg = (idx / (HOUT * HOUT)) % NCG;      // uniform per block (HOUT*HOUT >= 1024)
    int n  = idx / (HOUT * HOUT * NCG);

    for (int i = t; i < WSZ; i += 256) {
        int co = i % COB;
        int r  = i / COB;
        int kx = r % K, ky = (r / K) % K, ci = r / (K * K);
        wl[i] = w[(((cg * COB + co) * CIN + ci) * K + ky) * K + kx];
    }
    __syncthreads();

    float acc[COB];
    #pragma unroll
    for (int j = 0; j < COB; ++j) acc[j] = b[cg * COB + j];

    const float* inn = in + n * CIN * HIN * HIN;
    for (int ci = 0; ci < CIN; ++ci) {
        #pragma unroll
        for (int ky = 0; ky < K; ++ky) {
            int iy = y * S - P + ky;
            bool vy = (iy >= 0) && (iy < HIN);
            #pragma unroll
            for (int kx = 0; kx < K; ++kx) {
                int ix = x * S - P + kx;
                float v = (vy && ix >= 0 && ix < HIN) ? inn[(ci * HIN + iy) * HIN + ix] : 0.f;
                const float* wp = &wl[((ci * K + ky) * K + kx) * COB];
                if constexpr (COB % 4 == 0) {
                    #pragma unroll
                    for (int j4 = 0; j4 < COB / 4; ++j4) {
                        float4 wv = *(const float4*)(wp + j4 * 4);
                        acc[j4 * 4 + 0] = fmaf(v, wv.x, acc[j4 * 4 + 0]);
                        acc[j4 * 4 + 1] = fmaf(v, wv.y, acc[j4 * 4 + 1]);
                        acc[j4 * 4 + 2] = fmaf(v, wv.z, acc[j4 * 4 + 2]);
                        acc[j4 * 4 + 3] = fmaf(v, wv.w, acc[j4 * 4 + 3]);
                    }
                } else {
                    #pragma unroll
                    for (int j = 0; j < COB; ++j) acc[j] = fmaf(v, wp[j], acc[j]);
                }
            }
        }
    }
    #pragma unroll
    for (int j = 0; j < COB; ++j)
        out[((n * COUT + cg * COB + j) * HOUT + y) * HOUT + x] = leakyf(acc[j]);
}

// ---------- transposed conv (round-2 proven), ConvT weights (Cin,Cout,K,K) ---
template<int CIN, int COUT, int COB, int K, int S, int P, int HIN, int HOUT, int ACT>
__global__ __launch_bounds__(256) void convtf_k(const float* __restrict__ in,
                                                const float* __restrict__ w,
                                                const float* __restrict__ b,
                                                float* __restrict__ out)
{
    constexpr int NCG = COUT / COB;
    constexpr int WSZ = CIN * K * K * COB;
    constexpr int NTAP = K / S;
    __shared__ float wl[WSZ];
    int t = threadIdx.x;
    int idx = blockIdx.x * 256 + t;
    int x  = idx % HOUT;
    int y  = (idx / HOUT) % HOUT;
    int cg = (idx / (HOUT * HOUT)) % NCG;
    int n  = idx / (HOUT * HOUT * NCG);

    for (int i = t; i < WSZ; i += 256) {
        int co = i % COB;
        int r  = i / COB;
        int kx = r % K, ky = (r / K) % K, ci = r / (K * K);
        wl[i] = w[((ci * COUT + cg * COB + co) * K + ky) * K + kx];
    }
    __syncthreads();

    float acc[COB];
    #pragma unroll
    for (int j = 0; j < COB; ++j) acc[j] = b[cg * COB + j];

    int py = (y + P) % S;
    int px = (x + P) % S;
    const float* inn = in + n * CIN * HIN * HIN;
    for (int ci = 0; ci < CIN; ++ci) {
        #pragma unroll
        for (int ty = 0; ty < NTAP; ++ty) {
            int ky = py + ty * S;
            int iy = (y + P - ky) / S;
            bool vy = (ky < K) && (iy >= 0) && (iy < HIN);
            #pragma unroll
            for (int tx = 0; tx < NTAP; ++tx) {
                int kx = px + tx * S;
                int ix = (x + P - kx) / S;
                float v = (vy && kx < K && ix >= 0 && ix < HIN)
                              ? inn[(ci * HIN + iy) * HIN + ix] : 0.f;
                const float* wp = &wl[((ci * K + ky) * K + kx) * COB];
                if constexpr (COB % 4 == 0) {
                    #pragma unroll
                    for (int j4 = 0; j4 < COB / 4; ++j4) {
                        float4 wv = *(const float4*)(wp + j4 * 4);
                        acc[j4 * 4 + 0] = fmaf(v, wv.x, acc[j4 * 4 + 0]);
                        acc[j4 * 4 + 1] = fmaf(v, wv.y, acc[j4 * 4 + 1]);
                        acc[j4 * 4 + 2] = fmaf(v, wv.z, acc[j4 * 4 + 2]);
                        acc[j4 * 4 + 3] = fmaf(v, wv.w, acc[j4 * 4 + 3]);
                    }
                } else {
                    #pragma unroll
                    for (int j = 0; j < COB; ++j) acc[j] = fmaf(v, wp[j], acc[j]);
                }
            }
        }
    }
    #pragma unroll
    for (int j = 0; j < COB; ++j) {
        float r = acc[j];
        out[((n * COUT + cg * COB + j) * HOUT + y) * HOUT + x] =
            (ACT == 0) ? leakyf(r) : tanhf(r);
    }
}

// ---------- e4 (1x1 conv) materializing F[m][64] row-major ----------
__global__ __launch_bounds__(256) void e4f_k(const float* __restrict__ h3,
                                             const float* __restrict__ w4t,
                                             const float* __restrict__ eb4,
                                             float* __restrict__ F)
{
    int id = blockIdx.x * 256 + threadIdx.x;   // 4194304
    int d = id & 63;
    int m = rfl(id >> 6);                      // wave-uniform row
    int n = m >> 10, pos = m & 1023;
    const float* hp = h3 + (n << 14) + pos;    // uniform -> s_load
    float a = eb4[d];
    #pragma unroll
    for (int ci = 0; ci < 16; ++ci)
        a = fmaf(hp[ci << 10], w4t[(ci << 6) + d], a);
    F[id] = leakyf(a);
}

// ---------- VQ: lane <-> code, F rows via SGPR; zero lgkm ops in inner loop --
// Each lane holds one code column (32 VGPR, D split in 2 halves).
// Wave handles 16 rows (2 chunks x 8). best/idx per (lane,row), exact
// (score, idx) shuffle reduce at the end -> reference first-min semantics.
__global__ __launch_bounds__(256) void vqg_k(const float* __restrict__ F,
                                             const float* __restrict__ cb,
                                             const float* __restrict__ c2,
                                             int* __restrict__ idxOut,
                                             float* __restrict__ lossAcc)
{
    int t = threadIdx.x, lane = t & 63;
    int wid = rfl((blockIdx.x << 2) + (t >> 6));   // 4096 waves
    int row0 = wid << 4;                           // 16 rows per wave
    float wloss = 0.f;

    #pragma unroll 1
    for (int ch = 0; ch < 2; ++ch) {
        int rbase = row0 + (ch << 3);
        float best[8]; int bk[8];
        #pragma unroll
        for (int r = 0; r < 8; ++r) { best[r] = 3.4e38f; bk[r] = 0; }

        #pragma unroll 1
        for (int g = 0; g < 8; ++g) {
            int k0 = g << 6;
            float c2v = c2[k0 + lane];
            const float4* cp = (const float4*)(cb + ((k0 + lane) << 6));
            float acc[8] = {};
            {   // half 0: d = 0..31
                float ck[32];
                #pragma unroll
                for (int q = 0; q < 8; ++q) {
                    float4 v = cp[q];
                    ck[q * 4 + 0] = v.x; ck[q * 4 + 1] = v.y;
                    ck[q * 4 + 2] = v.z; ck[q * 4 + 3] = v.w;
                }
                #pragma unroll
                for (int i = 0; i < 32; ++i) {
                    float cv = ck[i];
                    #pragma unroll
                    for (int r = 0; r < 8; ++r)
                        acc[r] = fmaf(F[((rbase + r) << 6) + i], cv, acc[r]);
                }
            }
            {   // half 1: d = 32..63
                float ck[32];
                #pragma unroll
                for (int q = 0; q < 8; ++q) {
                    float4 v = cp[8 + q];
                    ck[q * 4 + 0] = v.x; ck[q * 4 + 1] = v.y;
                    ck[q * 4 + 2] = v.z; ck[q * 4 + 3] = v.w;
                }
                #pragma unroll
                for (int i = 0; i < 32; ++i) {
                    float cv = ck[i];
                    #pragma unroll
                    for (int r = 0; r < 8; ++r)
                        acc[r] = fmaf(F[((rbase + r) << 6) + 32 + i], cv, acc[r]);
                }
            }
            #pragma unroll
            for (int r = 0; r < 8; ++r) {
                float s = fmaf(0.5f, c2v, -acc[r]);
                if (s < best[r]) { best[r] = s; bk[r] = k0 + lane; }
            }
        }

        // per-row exact argmin reduce + idx store + fused loss
        #pragma unroll 1
        for (int r = 0; r < 8; ++r) {
            float bs = best[r]; int bi = bk[r];
            #pragma unroll
            for (int off = 32; off; off >>= 1) {
                float s2 = __shfl_down(bs, off, 64);
                int   i2 = __shfl_down(bi, off, 64);
                if (s2 < bs || (s2 == bs && i2 < bi)) { bs = s2; bi = i2; }
            }
            bi = __shfl(bi, 0, 64);
            int row = rbase + r;
            if (lane == 0) idxOut[row] = bi;
            float fv = F[(row << 6) + lane];
            float cv = cb[(bi << 6) + lane];
            float e = cv - fv;
            float p = e * e;
            #pragma unroll
            for (int off = 32; off; off >>= 1) p += __shfl_down(p, off, 64);
            if (lane == 0) wloss += p;
        }
    }
    if (lane == 0) atomicAdd(lossAcc, wloss);
}

// ---------- decoder conv1 via U-table ----------
__global__ __launch_bounds__(256) void d1_k(const int* __restrict__ idx,
                                            const float* __restrict__ U,
                                            const float* __restrict__ db1,
                                            float* __restrict__ out)
{
    int id = blockIdx.x * 256 + threadIdx.x;          // 262144
    int x = id & 31, y = (id >> 5) & 31;
    int cg = rfl((id >> 10) & 3), n = id >> 12;
    float acc[4];
    #pragma unroll
    for (int j = 0; j < 4; ++j) acc[j] = db1[cg * 4 + j];
    const float4* U4 = (const float4*)U;
    #pragma unroll
    for (int tap = 0; tap < 9; ++tap) {
        int yy = y + tap / 3 - 1, xx = x + tap % 3 - 1;
        if (yy < 0 || yy > 31 || xx < 0 || xx > 31) continue;
        int k = idx[(n << 10) + (yy << 5) + xx];
        float4 u = U4[(k * 9 + tap) * 4 + cg];
        acc[0] += u.x; acc[1] += u.y; acc[2] += u.z; acc[3] += u.w;
    }
    #pragma unroll
    for (int j = 0; j < 4; ++j)
        out[((n * 16 + cg * 4 + j) << 10) + (y << 5) + x] = leakyf(acc[j]);
}

__global__ void loss_k(const float* __restrict__ acc, float* __restrict__ out)
{
    out[0] = 1.25f * acc[0] / 4194304.0f;
}

extern "C" void kernel_launch(void* const* d_in, const int* in_sizes, int n_in,
                              void* d_out, int out_size, void* d_ws, size_t ws_size,
                              hipStream_t stream)
{
    const float* x        = (const float*)d_in[0];
    const float* ew1      = (const float*)d_in[1];
    const float* eb1      = (const float*)d_in[2];
    const float* ew2      = (const float*)d_in[3];
    const float* eb2      = (const float*)d_in[4];
    const float* ew3      = (const float*)d_in[5];
    const float* eb3      = (const float*)d_in[6];
    const float* ew4      = (const float*)d_in[7];
    const float* eb4      = (const float*)d_in[8];
    const float* codebook = (const float*)d_in[9];
    const float* dw1      = (const float*)d_in[10];
    const float* db1      = (const float*)d_in[11];
    const float* dw2      = (const float*)d_in[12];
    const float* db2      = (const float*)d_in[13];
    const float* dw3      = (const float*)d_in[14];
    const float* db3      = (const float*)d_in[15];

    float* out = (float*)d_out;
    float* ws  = (float*)d_ws;
    float* A    = ws + OFF_A;
    float* B    = ws + OFF_B;
    float* C    = ws + OFF_C;
    float* F    = ws + OFF_F;
    float* D1   = ws + OFF_D1;
    float* D2   = ws + OFF_D2;
    int*   IDX  = (int*)(ws + OFF_IDX);
    float* U    = ws + OFF_U;
    float* C2   = ws + OFF_C2;
    float* W4T  = ws + OFF_W4T;
    float* DWT  = ws + OFF_DWT;
    float* LOSS = ws + OFF_LOSS;

    hipMemsetAsync(LOSS, 0, sizeof(float), stream);
    prep_k<<<42, 256, 0, stream>>>(ew4, dw1, codebook, ws);
    uprep_k<<<288, 256, 0, stream>>>(DWT, codebook, U);

    convf_k<1, 8, 8, 4, 2, 1, 128, 64><<<1024, 256, 0, stream>>>(x, ew1, eb1, A);
    convf_k<8, 16, 4, 4, 2, 1, 64, 32><<<1024, 256, 0, stream>>>(A, ew2, eb2, B);
    convf_k<16, 16, 4, 3, 1, 1, 32, 32><<<1024, 256, 0, stream>>>(B, ew3, eb3, C);
    e4f_k<<<16384, 256, 0, stream>>>(C, W4T, eb4, F);

    vqg_k<<<1024, 256, 0, stream>>>(F, codebook, C2, IDX, LOSS);

    d1_k<<<1024, 256, 0, stream>>>(IDX, U, db1, D1);
    convtf_k<16, 8, 8, 4, 2, 1, 32, 64, 0><<<1024, 256, 0, stream>>>(D1, dw2, db2, D2);
    convtf_k<8, 1, 1, 4, 2, 1, 64, 128, 1><<<4096, 256, 0, stream>>>(D2, dw3, db3, out);

    loss_k<<<1, 1, 0, stream>>>(LOSS, out + 1048576);
}

// Round 8
// 162.039 us; speedup vs baseline: 2.5067x; 1.6889x over previous
//
#include <hip/hip_runtime.h>
#include <math.h>

#define DEV __device__ __forceinline__
DEV float leakyf(float v) { return v >= 0.f ? v : 0.01f * v; }
DEV int rfl(int v) { return __builtin_amdgcn_readfirstlane(v); }

// ---- ws layout (float offsets) ----
#define OFF_A    0u          // h1  [64][8][64][64]   2097152
#define OFF_B    2097152u    // h2  [64][16][32][32]  1048576
#define OFF_C    3145728u    // h3  [64][16][32][32]  1048576
#define OFF_D1   8388608u    // d1  [64][16][32][32]  1048576
#define OFF_D2   9437184u    // dt2 [64][8][64][64]   2097152
#define OFF_IDX  11534336u   // 65536 int32
#define OFF_U    11599872u   // 73728 [k512][tap9][co16]
#define OFF_C2   11673600u   // 512
#define OFF_W4T  11674112u   // 1024 [ci16][d64]
#define OFF_DWT  11675136u   // 9216 [ci64][tap9*16+co16]
#define OFF_LOSS 11684352u   // 1

// ---------- prep: W4T transpose, |c|^2, dw1 transpose ----------
__global__ void prep_k(const float* __restrict__ ew4, const float* __restrict__ dw1,
                       const float* __restrict__ cb, float* __restrict__ ws)
{
    int b = blockIdx.x, t = threadIdx.x;
    if (b < 4) {                      // W4T: [ci*64+d] = ew4[d][ci]
        int id = b * 256 + t;
        int d = id & 63, ci = id >> 6;
        ws[OFF_W4T + id] = ew4[d * 16 + ci];
    } else if (b < 6) {               // C2
        int k = (b - 4) * 256 + t;
        float s = 0.f;
        #pragma unroll
        for (int d = 0; d < 64; ++d) { float v = cb[k * 64 + d]; s = fmaf(v, v, s); }
        ws[OFF_C2 + k] = s;
    } else {                          // DWT: [ci*144 + tap*16 + co] = dw1[co][ci][tap]
        int id = (b - 6) * 256 + t;
        if (id < 9216) {
            int co = id & 15, tap = (id >> 4) % 9, ci = id / 144;
            ws[OFF_DWT + id] = dw1[(co * 64 + ci) * 9 + tap];
        }
    }
}

// U[k][tap][co] = sum_ci dwT[ci][tap*16+co] * cb[k][ci]
__global__ void uprep_k(const float* __restrict__ dwT, const float* __restrict__ cb,
                        float* __restrict__ U)
{
    int id = blockIdx.x * 256 + threadIdx.x;   // 73728 = k*144 + (tap*16+co)
    int k = id / 144;
    int r = id - k * 144;
    float s = 0.f;
    #pragma unroll
    for (int ci = 0; ci < 64; ++ci)
        s = fmaf(cb[k * 64 + ci], dwT[ci * 144 + r], s);
    U[id] = s;
}

// ---------- forward conv (round-2 proven): thread = spatial pos, COB chans ---
template<int CIN, int COUT, int COB, int K, int S, int P, int HIN, int HOUT>
__global__ __launch_bounds__(256) void convf_k(const float* __restrict__ in,
                                               const float* __restrict__ w,
                                               const float* __restrict__ b,
                                               float* __restrict__ out)
{
    constexpr int NCG = COUT / COB;
    constexpr int WSZ = CIN * K * K * COB;
    __shared__ float wl[WSZ];
    int t = threadIdx.x;
    int idx = blockIdx.x * 256 + t;
    int x  = idx % HOUT;
    int y  = (idx / HOUT) % HOUT;
    int cg = (idx / (HOUT * HOUT)) % NCG;      // uniform per block (HOUT*HOUT >= 1024)
    int n  = idx / (HOUT * HOUT * NCG);

    for (int i = t; i < WSZ; i += 256) {
        int co = i % COB;
        int r  = i / COB;
        int kx = r % K, ky = (r / K) % K, ci = r / (K * K);
        wl[i] = w[(((cg * COB + co) * CIN + ci) * K + ky) * K + kx];
    }
    __syncthreads();

    float acc[COB];
    #pragma unroll
    for (int j = 0; j < COB; ++j) acc[j] = b[cg * COB + j];

    const float* inn = in + n * CIN * HIN * HIN;
    for (int ci = 0; ci < CIN; ++ci) {
        #pragma unroll
        for (int ky = 0; ky < K; ++ky) {
            int iy = y * S - P + ky;
            bool vy = (iy >= 0) && (iy < HIN);
            #pragma unroll
            for (int kx = 0; kx < K; ++kx) {
                int ix = x * S - P + kx;
                float v = (vy && ix >= 0 && ix < HIN) ? inn[(ci * HIN + iy) * HIN + ix] : 0.f;
                const float* wp = &wl[((ci * K + ky) * K + kx) * COB];
                if constexpr (COB % 4 == 0) {
                    #pragma unroll
                    for (int j4 = 0; j4 < COB / 4; ++j4) {
                        float4 wv = *(const float4*)(wp + j4 * 4);
                        acc[j4 * 4 + 0] = fmaf(v, wv.x, acc[j4 * 4 + 0]);
                        acc[j4 * 4 + 1] = fmaf(v, wv.y, acc[j4 * 4 + 1]);
                        acc[j4 * 4 + 2] = fmaf(v, wv.z, acc[j4 * 4 + 2]);
                        acc[j4 * 4 + 3] = fmaf(v, wv.w, acc[j4 * 4 + 3]);
                    }
                } else {
                    #pragma unroll
                    for (int j = 0; j < COB; ++j) acc[j] = fmaf(v, wp[j], acc[j]);
                }
            }
        }
    }
    #pragma unroll
    for (int j = 0; j < COB; ++j)
        out[((n * COUT + cg * COB + j) * HOUT + y) * HOUT + x] = leakyf(acc[j]);
}

// ---------- transposed conv (round-2 proven), ConvT weights (Cin,Cout,K,K) ---
template<int CIN, int COUT, int COB, int K, int S, int P, int HIN, int HOUT, int ACT>
__global__ __launch_bounds__(256) void convtf_k(const float* __restrict__ in,
                                                const float* __restrict__ w,
                                                const float* __restrict__ b,
                                                float* __restrict__ out)
{
    constexpr int NCG = COUT / COB;
    constexpr int WSZ = CIN * K * K * COB;
    constexpr int NTAP = K / S;
    __shared__ float wl[WSZ];
    int t = threadIdx.x;
    int idx = blockIdx.x * 256 + t;
    int x  = idx % HOUT;
    int y  = (idx / HOUT) % HOUT;
    int cg = (idx / (HOUT * HOUT)) % NCG;
    int n  = idx / (HOUT * HOUT * NCG);

    for (int i = t; i < WSZ; i += 256) {
        int co = i % COB;
        int r  = i / COB;
        int kx = r % K, ky = (r / K) % K, ci = r / (K * K);
        wl[i] = w[((ci * COUT + cg * COB + co) * K + ky) * K + kx];
    }
    __syncthreads();

    float acc[COB];
    #pragma unroll
    for (int j = 0; j < COB; ++j) acc[j] = b[cg * COB + j];

    int py = (y + P) % S;
    int px = (x + P) % S;
    const float* inn = in + n * CIN * HIN * HIN;
    for (int ci = 0; ci < CIN; ++ci) {
        #pragma unroll
        for (int ty = 0; ty < NTAP; ++ty) {
            int ky = py + ty * S;
            int iy = (y + P - ky) / S;
            bool vy = (ky < K) && (iy >= 0) && (iy < HIN);
            #pragma unroll
            for (int tx = 0; tx < NTAP; ++tx) {
                int kx = px + tx * S;
                int ix = (x + P - kx) / S;
                float v = (vy && kx < K && ix >= 0 && ix < HIN)
                              ? inn[(ci * HIN + iy) * HIN + ix] : 0.f;
                const float* wp = &wl[((ci * K + ky) * K + kx) * COB];
                if constexpr (COB % 4 == 0) {
                    #pragma unroll
                    for (int j4 = 0; j4 < COB / 4; ++j4) {
                        float4 wv = *(const float4*)(wp + j4 * 4);
                        acc[j4 * 4 + 0] = fmaf(v, wv.x, acc[j4 * 4 + 0]);
                        acc[j4 * 4 + 1] = fmaf(v, wv.y, acc[j4 * 4 + 1]);
                        acc[j4 * 4 + 2] = fmaf(v, wv.z, acc[j4 * 4 + 2]);
                        acc[j4 * 4 + 3] = fmaf(v, wv.w, acc[j4 * 4 + 3]);
                    }
                } else {
                    #pragma unroll
                    for (int j = 0; j < COB; ++j) acc[j] = fmaf(v, wp[j], acc[j]);
                }
            }
        }
    }
    #pragma unroll
    for (int j = 0; j < COB; ++j) {
        float r = acc[j];
        out[((n * COUT + cg * COB + j) * HOUT + y) * HOUT + x] =
            (ACT == 0) ? leakyf(r) : tanhf(r);
    }
}

// ---------- fused e4 + VQ, register-tiled LDS GEMM ----------
// Block: 128 rows x 512 codes (4 panels of 128). 256 thr = 16(tr) x 16(tc),
// 8x8 tile/thread, both operands ds_read_b128 from XOR-swizzled LDS.
// F staged by computing e4 in-block (no F tensor in HBM at all).
__global__ __launch_bounds__(256) void vqh_k(const float* __restrict__ h3,
                                             const float* __restrict__ w4t,
                                             const float* __restrict__ eb4,
                                             const float* __restrict__ cb,
                                             const float* __restrict__ c2,
                                             int* __restrict__ idxOut,
                                             float* __restrict__ lossAcc)
{
    __shared__ float Fs[8192];     // [row128][d64], d XOR-swizzled by (row>>3)&7
    __shared__ float Cs[8192];     // [code128][d64], same swizzle; aliased by red
    int t = threadIdx.x;
    int row0 = blockIdx.x << 7;
    int n = row0 >> 10;            // whole block same image
    int pos0 = row0 & 1023;

    // ---- stage F = leaky(W4 h3 + b4) straight into LDS ----
    {
        int row = t & 127, dh = t >> 7;        // dh selects d in [dh*32, dh*32+32)
        const float* hp = h3 + (n << 14) + pos0 + row;
        float h[16];
        #pragma unroll
        for (int ci = 0; ci < 16; ++ci) h[ci] = hp[ci << 10];
        int rot = ((row >> 3) & 7) << 2;
        #pragma unroll
        for (int q = 0; q < 8; ++q) {
            int d0 = dh * 32 + q * 4;
            float a0 = eb4[d0 + 0], a1 = eb4[d0 + 1];
            float a2 = eb4[d0 + 2], a3 = eb4[d0 + 3];
            #pragma unroll
            for (int ci = 0; ci < 16; ++ci) {
                float v = h[ci];
                const float* wp = w4t + (ci << 6) + d0;
                a0 = fmaf(v, wp[0], a0); a1 = fmaf(v, wp[1], a1);
                a2 = fmaf(v, wp[2], a2); a3 = fmaf(v, wp[3], a3);
            }
            float4 wv = { leakyf(a0), leakyf(a1), leakyf(a2), leakyf(a3) };
            *(float4*)&Fs[(row << 6) + (d0 ^ rot)] = wv;
        }
    }

    int tr = t & 15, tc = t >> 4;
    int rotF = (tr & 7) << 2;      // rows tr*8+i all have (row>>3)==tr
    int rotC = (tc & 7) << 2;
    float best[8]; int bk[8];
    #pragma unroll
    for (int i = 0; i < 8; ++i) { best[i] = 3.4e38f; bk[i] = 0; }

    #pragma unroll 1
    for (int p = 0; p < 4; ++p) {
        __syncthreads();           // Fs ready (p=0) / prior Cs reads done
        {   // stage code panel p
            int code = t >> 1, dh = t & 1;
            int kk = (p << 7) + code;
            int rot = ((code >> 3) & 7) << 2;
            const float* src = cb + (kk << 6);
            #pragma unroll
            for (int q = 0; q < 8; ++q) {
                int d0 = dh * 32 + q * 4;
                *(float4*)&Cs[(code << 6) + (d0 ^ rot)] = *(const float4*)(src + d0);
            }
        }
        __syncthreads();

        float acc[8][8];
        #pragma unroll
        for (int i = 0; i < 8; ++i)
            #pragma unroll
            for (int j = 0; j < 8; ++j) acc[i][j] = 0.f;

        #pragma unroll 1
        for (int dc = 0; dc < 16; ++dc) {
            int d0 = dc << 2;
            float4 fv[8];
            #pragma unroll
            for (int i = 0; i < 8; ++i)
                fv[i] = *(const float4*)&Fs[((tr * 8 + i) << 6) + (d0 ^ rotF)];
            #pragma unroll
            for (int j = 0; j < 8; ++j) {
                float4 cv = *(const float4*)&Cs[((tc * 8 + j) << 6) + (d0 ^ rotC)];
                #pragma unroll
                for (int i = 0; i < 8; ++i) {
                    acc[i][j] = fmaf(fv[i].x, cv.x, acc[i][j]);
                    acc[i][j] = fmaf(fv[i].y, cv.y, acc[i][j]);
                    acc[i][j] = fmaf(fv[i].z, cv.z, acc[i][j]);
                    acc[i][j] = fmaf(fv[i].w, cv.w, acc[i][j]);
                }
            }
        }
        #pragma unroll
        for (int j = 0; j < 8; ++j) {
            int kk = (p << 7) + tc * 8 + j;            // ascending within thread
            float hc2 = 0.5f * c2[kk];
            #pragma unroll
            for (int i = 0; i < 8; ++i) {
                float s = hc2 - acc[i][j];
                if (s < best[i]) { best[i] = s; bk[i] = kk; }
            }
        }
    }

    __syncthreads();               // all Cs reads done; alias for reduction
    float* redS = Cs;              // [row][17]
    int*   redI = (int*)(Cs + 2176);
    #pragma unroll
    for (int i = 0; i < 8; ++i) {
        int row = tr * 8 + i;
        redS[row * 17 + tc] = best[i];
        redI[row * 17 + tc] = bk[i];
    }
    __syncthreads();
    if (t < 128) {
        int row = t;
        float bs = redS[row * 17]; int bi = redI[row * 17];
        #pragma unroll
        for (int c = 1; c < 16; ++c) {    // (score, idx) lexicographic = first-min
            float s2 = redS[row * 17 + c];
            int   i2 = redI[row * 17 + c];
            if (s2 < bs || (s2 == bs && i2 < bi)) { bs = s2; bi = i2; }
        }
        idxOut[row0 + row] = bi;
        // loss: sum (cb[bi] - f)^2  (commitment == embedding in fwd)
        int rot = ((row >> 3) & 7) << 2;
        const float* cr = cb + (bi << 6);
        float rs = 0.f;
        #pragma unroll
        for (int q = 0; q < 16; ++q) {
            int d0 = q * 4;
            float4 fv = *(const float4*)&Fs[(row << 6) + (d0 ^ rot)];
            float e0 = cr[d0 + 0] - fv.x, e1 = cr[d0 + 1] - fv.y;
            float e2 = cr[d0 + 2] - fv.z, e3 = cr[d0 + 3] - fv.w;
            rs = fmaf(e0, e0, rs); rs = fmaf(e1, e1, rs);
            rs = fmaf(e2, e2, rs); rs = fmaf(e3, e3, rs);
        }
        #pragma unroll
        for (int off = 32; off; off >>= 1) rs += __shfl_down(rs, off, 64);
        if ((t & 63) == 0) atomicAdd(lossAcc, rs);
    }
}

// ---------- decoder conv1 via U-table ----------
__global__ __launch_bounds__(256) void d1_k(const int* __restrict__ idx,
                                            const float* __restrict__ U,
                                            const float* __restrict__ db1,
                                            float* __restrict__ out)
{
    int id = blockIdx.x * 256 + threadIdx.x;          // 262144
    int x = id & 31, y = (id >> 5) & 31;
    int cg = rfl((id >> 10) & 3), n = id >> 12;
    float acc[4];
    #pragma unroll
    for (int j = 0; j < 4; ++j) acc[j] = db1[cg * 4 + j];
    const float4* U4 = (const float4*)U;
    #pragma unroll
    for (int tap = 0; tap < 9; ++tap) {
        int yy = y + tap / 3 - 1, xx = x + tap % 3 - 1;
        if (yy < 0 || yy > 31 || xx < 0 || xx > 31) continue;
        int k = idx[(n << 10) + (yy << 5) + xx];
        float4 u = U4[(k * 9 + tap) * 4 + cg];
        acc[0] += u.x; acc[1] += u.y; acc[2] += u.z; acc[3] += u.w;
    }
    #pragma unroll
    for (int j = 0; j < 4; ++j)
        out[((n * 16 + cg * 4 + j) << 10) + (y << 5) + x] = leakyf(acc[j]);
}

__global__ void loss_k(const float* __restrict__ acc, float* __restrict__ out)
{
    out[0] = 1.25f * acc[0] / 4194304.0f;
}

extern "C" void kernel_launch(void* const* d_in, const int* in_sizes, int n_in,
                              void* d_out, int out_size, void* d_ws, size_t ws_size,
                              hipStream_t stream)
{
    const float* x        = (const float*)d_in[0];
    const float* ew1      = (const float*)d_in[1];
    const float* eb1      = (const float*)d_in[2];
    const float* ew2      = (const float*)d_in[3];
    const float* eb2      = (const float*)d_in[4];
    const float* ew3      = (const float*)d_in[5];
    const float* eb3      = (const float*)d_in[6];
    const float* ew4      = (const float*)d_in[7];
    const float* eb4      = (const float*)d_in[8];
    const float* codebook = (const float*)d_in[9];
    const float* dw1      = (const float*)d_in[10];
    const float* db1      = (const float*)d_in[11];
    const float* dw2      = (const float*)d_in[12];
    const float* db2      = (const float*)d_in[13];
    const float* dw3      = (const float*)d_in[14];
    const float* db3      = (const float*)d_in[15];

    float* out = (float*)d_out;
    float* ws  = (float*)d_ws;
    float* A    = ws + OFF_A;
    float* B    = ws + OFF_B;
    float* C    = ws + OFF_C;
    float* D1   = ws + OFF_D1;
    float* D2   = ws + OFF_D2;
    int*   IDX  = (int*)(ws + OFF_IDX);
    float* U    = ws + OFF_U;
    float* C2   = ws + OFF_C2;
    float* W4T  = ws + OFF_W4T;
    float* DWT  = ws + OFF_DWT;
    float* LOSS = ws + OFF_LOSS;

    hipMemsetAsync(LOSS, 0, sizeof(float), stream);
    prep_k<<<42, 256, 0, stream>>>(ew4, dw1, codebook, ws);
    uprep_k<<<288, 256, 0, stream>>>(DWT, codebook, U);

    convf_k<1, 8, 8, 4, 2, 1, 128, 64><<<1024, 256, 0, stream>>>(x, ew1, eb1, A);
    convf_k<8, 16, 4, 4, 2, 1, 64, 32><<<1024, 256, 0, stream>>>(A, ew2, eb2, B);
    convf_k<16, 16, 4, 3, 1, 1, 32, 32><<<1024, 256, 0, stream>>>(B, ew3, eb3, C);

    vqh_k<<<512, 256, 0, stream>>>(C, W4T, eb4, codebook, C2, IDX, LOSS);

    d1_k<<<1024, 256, 0, stream>>>(IDX, U, db1, D1);
    convtf_k<16, 8, 8, 4, 2, 1, 32, 64, 0><<<1024, 256, 0, stream>>>(D1, dw2, db2, D2);
    convtf_k<8, 1, 1, 4, 2, 1, 64, 128, 1><<<4096, 256, 0, stream>>>(D2, dw3, db3, out);

    loss_k<<<1, 1, 0, stream>>>(LOSS, out + 1048576);
}

// Round 9
// 148.906 us; speedup vs baseline: 2.7277x; 1.0882x over previous
//
#include <hip/hip_runtime.h>
#include <math.h>

#define DEV __device__ __forceinline__
DEV float leakyf(float v) { return v >= 0.f ? v : 0.01f * v; }
DEV int rfl(int v) { return __builtin_amdgcn_readfirstlane(v); }

// ---- ws layout (float offsets) ----
#define OFF_A    0u          // h1  [64][8][64][64]   2097152
#define OFF_B    2097152u    // h2  [64][16][32][32]  1048576
#define OFF_C    3145728u    // h3  [64][16][32][32]  1048576
#define OFF_D1   8388608u    // d1  [64][16][32][32]  1048576
#define OFF_D2   9437184u    // dt2 [64][8][64][64]   2097152
#define OFF_IDX  11534336u   // 65536 int32
#define OFF_U    11599872u   // 73728 [k512][tap9][co16]
#define OFF_C2   11673600u   // 512
#define OFF_W4T  11674112u   // 1024 [ci16][d64]
#define OFF_DWT  11675136u   // 9216 [ci64][tap9*16+co16]
#define OFF_LOSS 11684352u   // 1

// ---------- prep: W4T transpose, |c|^2, dw1 transpose ----------
__global__ void prep_k(const float* __restrict__ ew4, const float* __restrict__ dw1,
                       const float* __restrict__ cb, float* __restrict__ ws)
{
    int b = blockIdx.x, t = threadIdx.x;
    if (b < 4) {                      // W4T: [ci*64+d] = ew4[d][ci]
        int id = b * 256 + t;
        int d = id & 63, ci = id >> 6;
        ws[OFF_W4T + id] = ew4[d * 16 + ci];
    } else if (b < 6) {               // C2
        int k = (b - 4) * 256 + t;
        float s = 0.f;
        #pragma unroll
        for (int d = 0; d < 64; ++d) { float v = cb[k * 64 + d]; s = fmaf(v, v, s); }
        ws[OFF_C2 + k] = s;
    } else {                          // DWT: [ci*144 + tap*16 + co] = dw1[co][ci][tap]
        int id = (b - 6) * 256 + t;
        if (id < 9216) {
            int co = id & 15, tap = (id >> 4) % 9, ci = id / 144;
            ws[OFF_DWT + id] = dw1[(co * 64 + ci) * 9 + tap];
        }
    }
}

// U[k][tap][co] = sum_ci dwT[ci][tap*16+co] * cb[k][ci]
__global__ void uprep_k(const float* __restrict__ dwT, const float* __restrict__ cb,
                        float* __restrict__ U)
{
    int id = blockIdx.x * 256 + threadIdx.x;   // 73728 = k*144 + (tap*16+co)
    int k = id / 144;
    int r = id - k * 144;
    float s = 0.f;
    #pragma unroll
    for (int ci = 0; ci < 64; ++ci)
        s = fmaf(cb[k * 64 + ci], dwT[ci * 144 + r], s);
    U[id] = s;
}

// ---------- forward conv (round-2 proven): thread = spatial pos, COB chans ---
template<int CIN, int COUT, int COB, int K, int S, int P, int HIN, int HOUT>
__global__ __launch_bounds__(256) void convf_k(const float* __restrict__ in,
                                               const float* __restrict__ w,
                                               const float* __restrict__ b,
                                               float* __restrict__ out)
{
    constexpr int NCG = COUT / COB;
    constexpr int WSZ = CIN * K * K * COB;
    __shared__ float wl[WSZ];
    int t = threadIdx.x;
    int idx = blockIdx.x * 256 + t;
    int x  = idx % HOUT;
    int y  = (idx / HOUT) % HOUT;
    int cg = (idx / (HOUT * HOUT)) % NCG;      // uniform per block (HOUT*HOUT >= 1024)
    int n  = idx / (HOUT * HOUT * NCG);

    for (int i = t; i < WSZ; i += 256) {
        int co = i % COB;
        int r  = i / COB;
        int kx = r % K, ky = (r / K) % K, ci = r / (K * K);
        wl[i] = w[(((cg * COB + co) * CIN + ci) * K + ky) * K + kx];
    }
    __syncthreads();

    float acc[COB];
    #pragma unroll
    for (int j = 0; j < COB; ++j) acc[j] = b[cg * COB + j];

    const float* inn = in + n * CIN * HIN * HIN;
    for (int ci = 0; ci < CIN; ++ci) {
        #pragma unroll
        for (int ky = 0; ky < K; ++ky) {
            int iy = y * S - P + ky;
            bool vy = (iy >= 0) && (iy < HIN);
            #pragma unroll
            for (int kx = 0; kx < K; ++kx) {
                int ix = x * S - P + kx;
                float v = (vy && ix >= 0 && ix < HIN) ? inn[(ci * HIN + iy) * HIN + ix] : 0.f;
                const float* wp = &wl[((ci * K + ky) * K + kx) * COB];
                if constexpr (COB % 4 == 0) {
                    #pragma unroll
                    for (int j4 = 0; j4 < COB / 4; ++j4) {
                        float4 wv = *(const float4*)(wp + j4 * 4);
                        acc[j4 * 4 + 0] = fmaf(v, wv.x, acc[j4 * 4 + 0]);
                        acc[j4 * 4 + 1] = fmaf(v, wv.y, acc[j4 * 4 + 1]);
                        acc[j4 * 4 + 2] = fmaf(v, wv.z, acc[j4 * 4 + 2]);
                        acc[j4 * 4 + 3] = fmaf(v, wv.w, acc[j4 * 4 + 3]);
                    }
                } else {
                    #pragma unroll
                    for (int j = 0; j < COB; ++j) acc[j] = fmaf(v, wp[j], acc[j]);
                }
            }
        }
    }
    #pragma unroll
    for (int j = 0; j < COB; ++j)
        out[((n * COUT + cg * COB + j) * HOUT + y) * HOUT + x] = leakyf(acc[j]);
}

// ---------- transposed conv (round-2 proven), ConvT weights (Cin,Cout,K,K) ---
template<int CIN, int COUT, int COB, int K, int S, int P, int HIN, int HOUT, int ACT>
__global__ __launch_bounds__(256) void convtf_k(const float* __restrict__ in,
                                                const float* __restrict__ w,
                                                const float* __restrict__ b,
                                                float* __restrict__ out)
{
    constexpr int NCG = COUT / COB;
    constexpr int WSZ = CIN * K * K * COB;
    constexpr int NTAP = K / S;
    __shared__ float wl[WSZ];
    int t = threadIdx.x;
    int idx = blockIdx.x * 256 + t;
    int x  = idx % HOUT;
    int y  = (idx / HOUT) % HOUT;
    int cg = (idx / (HOUT * HOUT)) % NCG;
    int n  = idx / (HOUT * HOUT * NCG);

    for (int i = t; i < WSZ; i += 256) {
        int co = i % COB;
        int r  = i / COB;
        int kx = r % K, ky = (r / K) % K, ci = r / (K * K);
        wl[i] = w[((ci * COUT + cg * COB + co) * K + ky) * K + kx];
    }
    __syncthreads();

    float acc[COB];
    #pragma unroll
    for (int j = 0; j < COB; ++j) acc[j] = b[cg * COB + j];

    int py = (y + P) % S;
    int px = (x + P) % S;
    const float* inn = in + n * CIN * HIN * HIN;
    for (int ci = 0; ci < CIN; ++ci) {
        #pragma unroll
        for (int ty = 0; ty < NTAP; ++ty) {
            int ky = py + ty * S;
            int iy = (y + P - ky) / S;
            bool vy = (ky < K) && (iy >= 0) && (iy < HIN);
            #pragma unroll
            for (int tx = 0; tx < NTAP; ++tx) {
                int kx = px + tx * S;
                int ix = (x + P - kx) / S;
                float v = (vy && kx < K && ix >= 0 && ix < HIN)
                              ? inn[(ci * HIN + iy) * HIN + ix] : 0.f;
                const float* wp = &wl[((ci * K + ky) * K + kx) * COB];
                if constexpr (COB % 4 == 0) {
                    #pragma unroll
                    for (int j4 = 0; j4 < COB / 4; ++j4) {
                        float4 wv = *(const float4*)(wp + j4 * 4);
                        acc[j4 * 4 + 0] = fmaf(v, wv.x, acc[j4 * 4 + 0]);
                        acc[j4 * 4 + 1] = fmaf(v, wv.y, acc[j4 * 4 + 1]);
                        acc[j4 * 4 + 2] = fmaf(v, wv.z, acc[j4 * 4 + 2]);
                        acc[j4 * 4 + 3] = fmaf(v, wv.w, acc[j4 * 4 + 3]);
                    }
                } else {
                    #pragma unroll
                    for (int j = 0; j < COB; ++j) acc[j] = fmaf(v, wp[j], acc[j]);
                }
            }
        }
    }
    #pragma unroll
    for (int j = 0; j < COB; ++j) {
        float r = acc[j];
        out[((n * COUT + cg * COB + j) * HOUT + y) * HOUT + x] =
            (ACT == 0) ? leakyf(r) : tanhf(r);
    }
}

// ---------- fused e4 + VQ, d-major LDS GEMM ----------
// Fs[d64][row128], Cs[d64][code128]. 256 thr = 16(tr) x 16(tc).
// Thread tile: rows {4tr..4tr+3, 64+4tr..+3} x codes {4tc..4tc+3, 64+4tc..+3}.
// Per d: 4 ds_read_b128 (2-way/broadcast, conflict-free) -> 64 fma.
// Addresses = base + d*512B (immediate offsets, zero addr VALU).
__global__ __launch_bounds__(256) void vqh_k(const float* __restrict__ h3,
                                             const float* __restrict__ w4t,
                                             const float* __restrict__ eb4,
                                             const float* __restrict__ cb,
                                             const float* __restrict__ c2,
                                             int* __restrict__ idxOut,
                                             float* __restrict__ lossAcc)
{
    __shared__ float Fs[64 * 128];     // [d][row]  32 KB
    __shared__ float Cs[64 * 128];     // [d][code] 32 KB; aliased for reduction
    int t = threadIdx.x;
    int row0 = blockIdx.x << 7;
    int n = row0 >> 10;                // whole block same image
    int pos0 = row0 & 1023;

    // ---- stage F = leaky(W4 h3 + b4) into Fs[d][row] ----
    {
        int row = t & 127, dh = t >> 7;        // dh: d-half [dh*32, dh*32+32)
        const float* hp = h3 + (n << 14) + pos0 + row;
        float h[16];
        #pragma unroll
        for (int ci = 0; ci < 16; ++ci) h[ci] = hp[ci << 10];
        #pragma unroll
        for (int q = 0; q < 8; ++q) {
            int d0 = dh * 32 + q * 4;
            float a0 = eb4[d0 + 0], a1 = eb4[d0 + 1];
            float a2 = eb4[d0 + 2], a3 = eb4[d0 + 3];
            #pragma unroll
            for (int ci = 0; ci < 16; ++ci) {
                float v = h[ci];
                const float* wp = w4t + (ci << 6) + d0;
                a0 = fmaf(v, wp[0], a0); a1 = fmaf(v, wp[1], a1);
                a2 = fmaf(v, wp[2], a2); a3 = fmaf(v, wp[3], a3);
            }
            Fs[(d0 + 0) * 128 + row] = leakyf(a0);
            Fs[(d0 + 1) * 128 + row] = leakyf(a1);
            Fs[(d0 + 2) * 128 + row] = leakyf(a2);
            Fs[(d0 + 3) * 128 + row] = leakyf(a3);
        }
    }

    int tr = t & 15, tc = t >> 4;
    float best[8]; int bk[8];
    #pragma unroll
    for (int i = 0; i < 8; ++i) { best[i] = 3.4e38f; bk[i] = 0; }

    #pragma unroll 1
    for (int p = 0; p < 4; ++p) {
        __syncthreads();               // Fs ready (p=0) / prior Cs reads done
        {   // stage code panel p into Cs[d][code]
            int code = t >> 1, dh = t & 1;
            const float* src = cb + (((p << 7) + code) << 6) + dh * 32;
            #pragma unroll
            for (int q = 0; q < 8; ++q) {
                float4 v = *(const float4*)(src + q * 4);
                int d0 = dh * 32 + q * 4;
                Cs[(d0 + 0) * 128 + code] = v.x;
                Cs[(d0 + 1) * 128 + code] = v.y;
                Cs[(d0 + 2) * 128 + code] = v.z;
                Cs[(d0 + 3) * 128 + code] = v.w;
            }
        }
        __syncthreads();

        float acc[8][8];
        #pragma unroll
        for (int i = 0; i < 8; ++i)
            #pragma unroll
            for (int j = 0; j < 8; ++j) acc[i][j] = 0.f;

        const float* fp0 = &Fs[tr * 4];
        const float* fp1 = &Fs[64 + tr * 4];
        const float* cp0 = &Cs[tc * 4];
        const float* cp1 = &Cs[64 + tc * 4];
        #pragma unroll 8
        for (int d = 0; d < 64; ++d) {
            float4 f0 = *(const float4*)(fp0 + d * 128);
            float4 f1 = *(const float4*)(fp1 + d * 128);
            float4 c0 = *(const float4*)(cp0 + d * 128);
            float4 c1 = *(const float4*)(cp1 + d * 128);
            float f[8] = { f0.x, f0.y, f0.z, f0.w, f1.x, f1.y, f1.z, f1.w };
            float c[8] = { c0.x, c0.y, c0.z, c0.w, c1.x, c1.y, c1.z, c1.w };
            #pragma unroll
            for (int i = 0; i < 8; ++i)
                #pragma unroll
                for (int j = 0; j < 8; ++j)
                    acc[i][j] = fmaf(f[i], c[j], acc[i][j]);
        }
        #pragma unroll
        for (int j = 0; j < 8; ++j) {
            int kk = (p << 7) + (j < 4 ? tc * 4 + j : 64 + tc * 4 + j - 4); // ascending in j
            float hc2 = 0.5f * c2[kk];
            #pragma unroll
            for (int i = 0; i < 8; ++i) {
                float s = hc2 - acc[i][j];
                if (s < best[i]) { best[i] = s; bk[i] = kk; }
            }
        }
    }

    __syncthreads();               // all Cs reads done; alias for reduction
    float* redS = Cs;              // [row][17]
    int*   redI = (int*)(Cs + 2176);
    #pragma unroll
    for (int i = 0; i < 8; ++i) {
        int row = (i < 4) ? tr * 4 + i : 64 + tr * 4 + i - 4;
        redS[row * 17 + tc] = best[i];
        redI[row * 17 + tc] = bk[i];
    }
    __syncthreads();
    if (t < 128) {
        int row = t;
        float bs = redS[row * 17]; int bi = redI[row * 17];
        #pragma unroll
        for (int c = 1; c < 16; ++c) {    // (score, idx) lexicographic = first-min
            float s2 = redS[row * 17 + c];
            int   i2 = redI[row * 17 + c];
            if (s2 < bs || (s2 == bs && i2 < bi)) { bs = s2; bi = i2; }
        }
        idxOut[row0 + row] = bi;
        // loss: sum (cb[bi] - f)^2  (commitment == embedding in fwd)
        const float* cr = cb + (bi << 6);
        float rs = 0.f;
        #pragma unroll
        for (int d = 0; d < 64; ++d) {
            float e = cr[d] - Fs[d * 128 + row];
            rs = fmaf(e, e, rs);
        }
        #pragma unroll
        for (int off = 32; off; off >>= 1) rs += __shfl_down(rs, off, 64);
        if ((t & 63) == 0) atomicAdd(lossAcc, rs);
    }
}

// ---------- decoder conv1 via U-table ----------
__global__ __launch_bounds__(256) void d1_k(const int* __restrict__ idx,
                                            const float* __restrict__ U,
                                            const float* __restrict__ db1,
                                            float* __restrict__ out)
{
    int id = blockIdx.x * 256 + threadIdx.x;          // 262144
    int x = id & 31, y = (id >> 5) & 31;
    int cg = rfl((id >> 10) & 3), n = id >> 12;
    float acc[4];
    #pragma unroll
    for (int j = 0; j < 4; ++j) acc[j] = db1[cg * 4 + j];
    const float4* U4 = (const float4*)U;
    #pragma unroll
    for (int tap = 0; tap < 9; ++tap) {
        int yy = y + tap / 3 - 1, xx = x + tap % 3 - 1;
        if (yy < 0 || yy > 31 || xx < 0 || xx > 31) continue;
        int k = idx[(n << 10) + (yy << 5) + xx];
        float4 u = U4[(k * 9 + tap) * 4 + cg];
        acc[0] += u.x; acc[1] += u.y; acc[2] += u.z; acc[3] += u.w;
    }
    #pragma unroll
    for (int j = 0; j < 4; ++j)
        out[((n * 16 + cg * 4 + j) << 10) + (y << 5) + x] = leakyf(acc[j]);
}

__global__ void loss_k(const float* __restrict__ acc, float* __restrict__ out)
{
    out[0] = 1.25f * acc[0] / 4194304.0f;
}

extern "C" void kernel_launch(void* const* d_in, const int* in_sizes, int n_in,
                              void* d_out, int out_size, void* d_ws, size_t ws_size,
                              hipStream_t stream)
{
    const float* x        = (const float*)d_in[0];
    const float* ew1      = (const float*)d_in[1];
    const float* eb1      = (const float*)d_in[2];
    const float* ew2      = (const float*)d_in[3];
    const float* eb2      = (const float*)d_in[4];
    const float* ew3      = (const float*)d_in[5];
    const float* eb3      = (const float*)d_in[6];
    const float* ew4      = (const float*)d_in[7];
    const float* eb4      = (const float*)d_in[8];
    const float* codebook = (const float*)d_in[9];
    const float* dw1      = (const float*)d_in[10];
    const float* db1      = (const float*)d_in[11];
    const float* dw2      = (const float*)d_in[12];
    const float* db2      = (const float*)d_in[13];
    const float* dw3      = (const float*)d_in[14];
    const float* db3      = (const float*)d_in[15];

    float* out = (float*)d_out;
    float* ws  = (float*)d_ws;
    float* A    = ws + OFF_A;
    float* B    = ws + OFF_B;
    float* C    = ws + OFF_C;
    float* D1   = ws + OFF_D1;
    float* D2   = ws + OFF_D2;
    int*   IDX  = (int*)(ws + OFF_IDX);
    float* U    = ws + OFF_U;
    float* C2   = ws + OFF_C2;
    float* W4T  = ws + OFF_W4T;
    float* DWT  = ws + OFF_DWT;
    float* LOSS = ws + OFF_LOSS;

    hipMemsetAsync(LOSS, 0, sizeof(float), stream);
    prep_k<<<42, 256, 0, stream>>>(ew4, dw1, codebook, ws);
    uprep_k<<<288, 256, 0, stream>>>(DWT, codebook, U);

    convf_k<1, 8, 8, 4, 2, 1, 128, 64><<<1024, 256, 0, stream>>>(x, ew1, eb1, A);
    convf_k<8, 16, 4, 4, 2, 1, 64, 32><<<1024, 256, 0, stream>>>(A, ew2, eb2, B);
    convf_k<16, 16, 4, 3, 1, 1, 32, 32><<<1024, 256, 0, stream>>>(B, ew3, eb3, C);

    vqh_k<<<512, 256, 0, stream>>>(C, W4T, eb4, codebook, C2, IDX, LOSS);

    d1_k<<<1024, 256, 0, stream>>>(IDX, U, db1, D1);
    convtf_k<16, 8, 8, 4, 2, 1, 32, 64, 0><<<1024, 256, 0, stream>>>(D1, dw2, db2, D2);
    convtf_k<8, 1, 1, 4, 2, 1, 64, 128, 1><<<4096, 256, 0, stream>>>(D2, dw3, db3, out);

    loss_k<<<1, 1, 0, stream>>>(LOSS, out + 1048576);
}

// Round 10
// 148.618 us; speedup vs baseline: 2.7330x; 1.0019x over previous
//
#include <hip/hip_runtime.h>
#include <math.h>

#define DEV __device__ __forceinline__
DEV float leakyf(float v) { return v >= 0.f ? v : 0.01f * v; }
DEV int rfl(int v) { return __builtin_amdgcn_readfirstlane(v); }

struct F4 { float x, y, z, w; };   // natural align 4: legal on any float*

// ---- ws layout (float offsets) ----
#define OFF_XP   0u          // x padded [64][130][130]      1081600
#define OFF_H1P  1081600u    // h1 [64][8][66][66]           2230272
#define OFF_H2P  3311872u    // h2 [64][16][34][34]          1183744
#define OFF_H3   4495616u    // h3 [64][16][32][32]          1048576
#define OFF_D1P  5544192u    // d1 [64][16][34][34]          1183744
#define OFF_D2P  6727936u    // d2 [64][8][66][66]           2230272
#define OFF_IDX  8958208u    // 65536 int32
#define OFF_U    9023744u    // 73728 [k512][tap9][co16]
#define OFF_C2   9097472u    // 512
#define OFF_W4T  9097984u    // 1024 [ci16][d64]
#define OFF_DWT  9099008u    // 9216 [ci64][tap9*16+co16]
#define OFF_LOSS 9108224u    // 1

// ---------- prep: W4T transpose, |c|^2, dw1 transpose ----------
__global__ void prep_k(const float* __restrict__ ew4, const float* __restrict__ dw1,
                       const float* __restrict__ cb, float* __restrict__ ws)
{
    int b = blockIdx.x, t = threadIdx.x;
    if (b < 4) {                      // W4T: [ci*64+d] = ew4[d][ci]
        int id = b * 256 + t;
        int d = id & 63, ci = id >> 6;
        ws[OFF_W4T + id] = ew4[d * 16 + ci];
    } else if (b < 6) {               // C2
        int k = (b - 4) * 256 + t;
        float s = 0.f;
        #pragma unroll
        for (int d = 0; d < 64; ++d) { float v = cb[k * 64 + d]; s = fmaf(v, v, s); }
        ws[OFF_C2 + k] = s;
    } else {                          // DWT: [ci*144 + tap*16 + co] = dw1[co][ci][tap]
        int id = (b - 6) * 256 + t;
        if (id < 9216) {
            int co = id & 15, tap = (id >> 4) % 9, ci = id / 144;
            ws[OFF_DWT + id] = dw1[(co * 64 + ci) * 9 + tap];
        }
    }
}

// U[k][tap][co] = sum_ci dwT[ci][tap*16+co] * cb[k][ci]
__global__ void uprep_k(const float* __restrict__ dwT, const float* __restrict__ cb,
                        float* __restrict__ U)
{
    int id = blockIdx.x * 256 + threadIdx.x;   // 73728
    int k = id / 144;
    int r = id - k * 144;
    float s = 0.f;
    #pragma unroll
    for (int ci = 0; ci < 64; ++ci)
        s = fmaf(cb[k * 64 + ci], dwT[ci * 144 + r], s);
    U[id] = s;
}

// ---------- halo zeroing for padded buffers ----------
DEV void halo_store(float* base, int plane, int r, int W, int H, long psz)
{
    int row, col;
    if (r < W)          { row = 0;     col = r; }
    else if (r < 2 * W) { row = H - 1; col = r - W; }
    else { int r2 = r - 2 * W; row = 1 + (r2 >> 1); col = (r2 & 1) ? W - 1 : 0; }
    base[plane * psz + row * W + col] = 0.f;
}

__global__ void halo_k(float* __restrict__ ws)
{
    int id = blockIdx.x * 256 + threadIdx.x;       // 569600 total
    if (id < 33024) {                              // XP: 64 planes 130x130, 516/plane
        halo_store(ws + OFF_XP, id / 516, id % 516, 130, 130, 16900);
    } else if (id < 166144) {                      // H1P: 512 planes 66x66, 260/plane
        int i = id - 33024;
        halo_store(ws + OFF_H1P, i / 260, i % 260, 66, 66, 4356);
    } else if (id < 301312) {                      // H2P: 1024 planes 34x34, 132/plane
        int i = id - 166144;
        halo_store(ws + OFF_H2P, i / 132, i % 132, 34, 34, 1156);
    } else if (id < 436480) {                      // D1P
        int i = id - 301312;
        halo_store(ws + OFF_D1P, i / 132, i % 132, 34, 34, 1156);
    } else if (id < 569600) {                      // D2P
        int i = id - 436480;
        halo_store(ws + OFF_D2P, i / 260, i % 260, 66, 66, 4356);
    }
}

// ---------- pad x into XP ----------
__global__ void padx_k(const float* __restrict__ x, float* __restrict__ xp)
{
    int id = blockIdx.x * 256 + threadIdx.x;       // 1048576
    int ix = id & 127, iy = (id >> 7) & 127, n = id >> 14;
    xp[(n * 130 + iy + 1) * 130 + ix + 1] = x[id];
}

// ---------- e1: 1->8, K4 S2 P1, from XP ----------
__global__ __launch_bounds__(256) void e1p_k(const float* __restrict__ xp,
                                             const float* __restrict__ ew1,
                                             const float* __restrict__ eb1,
                                             float* __restrict__ h1p)
{
    __shared__ float wl[128];
    int t = threadIdx.x;
    if (t < 128) { int co = t & 7, tap = t >> 3; wl[t] = ew1[co * 16 + tap]; }
    __syncthreads();
    int id = blockIdx.x * 256 + t;                 // 262144
    int x = id & 63, y = (id >> 6) & 63, n = id >> 12;
    float acc[8];
    #pragma unroll
    for (int j = 0; j < 8; ++j) acc[j] = eb1[j];
    const float* base = xp + (n * 130 + 2 * y) * 130 + 2 * x;
    #pragma unroll
    for (int ky = 0; ky < 4; ++ky) {
        F4 v = *(const F4*)(base + ky * 130);
        float vv[4] = { v.x, v.y, v.z, v.w };
        #pragma unroll
        for (int kx = 0; kx < 4; ++kx) {
            const float* wp = &wl[(ky * 4 + kx) * 8];
            #pragma unroll
            for (int j = 0; j < 8; ++j) acc[j] = fmaf(vv[kx], wp[j], acc[j]);
        }
    }
    #pragma unroll
    for (int j = 0; j < 8; ++j)
        h1p[((n * 8 + j) * 66 + y + 1) * 66 + x + 1] = leakyf(acc[j]);
}

// ---------- e2: 8->16, K4 S2 P1, COB4 ----------
__global__ __launch_bounds__(256) void e2p_k(const float* __restrict__ h1p,
                                             const float* __restrict__ ew2,
                                             const float* __restrict__ eb2,
                                             float* __restrict__ h2p)
{
    __shared__ float wl[512];
    int t = threadIdx.x;
    int id = blockIdx.x * 256 + t;                 // 262144
    int x = id & 31, y = (id >> 5) & 31;
    int cg = rfl((id >> 10) & 3), n = id >> 12;
    {
        int i = t + (t < 256 ? 0 : 0);
        for (i = t; i < 512; i += 256) {
            int co = i & 3, r = i >> 2;
            int kx = r & 3, ky = (r >> 2) & 3, ci = r >> 4;
            wl[i] = ew2[((cg * 4 + co) * 8 + ci) * 16 + ky * 4 + kx];
        }
    }
    __syncthreads();
    float acc[4];
    #pragma unroll
    for (int j = 0; j < 4; ++j) acc[j] = eb2[cg * 4 + j];
    #pragma unroll 1
    for (int ci = 0; ci < 8; ++ci) {
        const float* base = h1p + ((n * 8 + ci) * 66 + 2 * y) * 66 + 2 * x;
        #pragma unroll
        for (int ky = 0; ky < 4; ++ky) {
            F4 v = *(const F4*)(base + ky * 66);
            float vv[4] = { v.x, v.y, v.z, v.w };
            #pragma unroll
            for (int kx = 0; kx < 4; ++kx) {
                const float* wp = &wl[((ci * 4 + ky) * 4 + kx) * 4];
                acc[0] = fmaf(vv[kx], wp[0], acc[0]);
                acc[1] = fmaf(vv[kx], wp[1], acc[1]);
                acc[2] = fmaf(vv[kx], wp[2], acc[2]);
                acc[3] = fmaf(vv[kx], wp[3], acc[3]);
            }
        }
    }
    #pragma unroll
    for (int j = 0; j < 4; ++j)
        h2p[((n * 16 + cg * 4 + j) * 34 + y + 1) * 34 + x + 1] = leakyf(acc[j]);
}

// ---------- e3: 16->16, K3 S1 P1, COB4; writes UNPADDED h3 ----------
__global__ __launch_bounds__(256) void e3p_k(const float* __restrict__ h2p,
                                             const float* __restrict__ ew3,
                                             const float* __restrict__ eb3,
                                             float* __restrict__ h3)
{
    __shared__ float wl[576];
    int t = threadIdx.x;
    int id = blockIdx.x * 256 + t;                 // 262144
    int x = id & 31, y = (id >> 5) & 31;
    int cg = rfl((id >> 10) & 3), n = id >> 12;
    for (int i = t; i < 576; i += 256) {
        int co = i & 3, r = i >> 2;
        int kx = r % 3, ky = (r / 3) % 3, ci = r / 9;
        wl[i] = ew3[((cg * 4 + co) * 16 + ci) * 9 + ky * 3 + kx];
    }
    __syncthreads();
    float acc[4];
    #pragma unroll
    for (int j = 0; j < 4; ++j) acc[j] = eb3[cg * 4 + j];
    #pragma unroll 1
    for (int ci = 0; ci < 16; ++ci) {
        const float* base = h2p + ((n * 16 + ci) * 34 + y) * 34 + x;
        #pragma unroll
        for (int ky = 0; ky < 3; ++ky) {
            F4 v = *(const F4*)(base + ky * 34);
            float vv[3] = { v.x, v.y, v.z };
            #pragma unroll
            for (int kx = 0; kx < 3; ++kx) {
                const float* wp = &wl[((ci * 3 + ky) * 3 + kx) * 4];
                acc[0] = fmaf(vv[kx], wp[0], acc[0]);
                acc[1] = fmaf(vv[kx], wp[1], acc[1]);
                acc[2] = fmaf(vv[kx], wp[2], acc[2]);
                acc[3] = fmaf(vv[kx], wp[3], acc[3]);
            }
        }
    }
    #pragma unroll
    for (int j = 0; j < 4; ++j)
        h3[((n * 16 + cg * 4 + j) << 10) + (y << 5) + x] = leakyf(acc[j]);
}

// ---------- fused e4 + VQ, d-major LDS GEMM (unchanged from r9) ----------
__global__ __launch_bounds__(256) void vqh_k(const float* __restrict__ h3,
                                             const float* __restrict__ w4t,
                                             const float* __restrict__ eb4,
                                             const float* __restrict__ cb,
                                             const float* __restrict__ c2,
                                             int* __restrict__ idxOut,
                                             float* __restrict__ lossAcc)
{
    __shared__ float Fs[64 * 128];
    __shared__ float Cs[64 * 128];
    int t = threadIdx.x;
    int row0 = blockIdx.x << 7;
    int n = row0 >> 10;
    int pos0 = row0 & 1023;

    {
        int row = t & 127, dh = t >> 7;
        const float* hp = h3 + (n << 14) + pos0 + row;
        float h[16];
        #pragma unroll
        for (int ci = 0; ci < 16; ++ci) h[ci] = hp[ci << 10];
        #pragma unroll
        for (int q = 0; q < 8; ++q) {
            int d0 = dh * 32 + q * 4;
            float a0 = eb4[d0 + 0], a1 = eb4[d0 + 1];
            float a2 = eb4[d0 + 2], a3 = eb4[d0 + 3];
            #pragma unroll
            for (int ci = 0; ci < 16; ++ci) {
                float v = h[ci];
                const float* wp = w4t + (ci << 6) + d0;
                a0 = fmaf(v, wp[0], a0); a1 = fmaf(v, wp[1], a1);
                a2 = fmaf(v, wp[2], a2); a3 = fmaf(v, wp[3], a3);
            }
            Fs[(d0 + 0) * 128 + row] = leakyf(a0);
            Fs[(d0 + 1) * 128 + row] = leakyf(a1);
            Fs[(d0 + 2) * 128 + row] = leakyf(a2);
            Fs[(d0 + 3) * 128 + row] = leakyf(a3);
        }
    }

    int tr = t & 15, tc = t >> 4;
    float best[8]; int bk[8];
    #pragma unroll
    for (int i = 0; i < 8; ++i) { best[i] = 3.4e38f; bk[i] = 0; }

    #pragma unroll 1
    for (int p = 0; p < 4; ++p) {
        __syncthreads();
        {
            int code = t >> 1, dh = t & 1;
            const float* src = cb + (((p << 7) + code) << 6) + dh * 32;
            #pragma unroll
            for (int q = 0; q < 8; ++q) {
                float4 v = *(const float4*)(src + q * 4);
                int d0 = dh * 32 + q * 4;
                Cs[(d0 + 0) * 128 + code] = v.x;
                Cs[(d0 + 1) * 128 + code] = v.y;
                Cs[(d0 + 2) * 128 + code] = v.z;
                Cs[(d0 + 3) * 128 + code] = v.w;
            }
        }
        __syncthreads();

        float acc[8][8];
        #pragma unroll
        for (int i = 0; i < 8; ++i)
            #pragma unroll
            for (int j = 0; j < 8; ++j) acc[i][j] = 0.f;

        const float* fp0 = &Fs[tr * 4];
        const float* fp1 = &Fs[64 + tr * 4];
        const float* cp0 = &Cs[tc * 4];
        const float* cp1 = &Cs[64 + tc * 4];
        #pragma unroll 8
        for (int d = 0; d < 64; ++d) {
            float4 f0 = *(const float4*)(fp0 + d * 128);
            float4 f1 = *(const float4*)(fp1 + d * 128);
            float4 c0 = *(const float4*)(cp0 + d * 128);
            float4 c1 = *(const float4*)(cp1 + d * 128);
            float f[8] = { f0.x, f0.y, f0.z, f0.w, f1.x, f1.y, f1.z, f1.w };
            float c[8] = { c0.x, c0.y, c0.z, c0.w, c1.x, c1.y, c1.z, c1.w };
            #pragma unroll
            for (int i = 0; i < 8; ++i)
                #pragma unroll
                for (int j = 0; j < 8; ++j)
                    acc[i][j] = fmaf(f[i], c[j], acc[i][j]);
        }
        #pragma unroll
        for (int j = 0; j < 8; ++j) {
            int kk = (p << 7) + (j < 4 ? tc * 4 + j : 64 + tc * 4 + j - 4);
            float hc2 = 0.5f * c2[kk];
            #pragma unroll
            for (int i = 0; i < 8; ++i) {
                float s = hc2 - acc[i][j];
                if (s < best[i]) { best[i] = s; bk[i] = kk; }
            }
        }
    }

    __syncthreads();
    float* redS = Cs;
    int*   redI = (int*)(Cs + 2176);
    #pragma unroll
    for (int i = 0; i < 8; ++i) {
        int row = (i < 4) ? tr * 4 + i : 64 + tr * 4 + i - 4;
        redS[row * 17 + tc] = best[i];
        redI[row * 17 + tc] = bk[i];
    }
    __syncthreads();
    if (t < 128) {
        int row = t;
        float bs = redS[row * 17]; int bi = redI[row * 17];
        #pragma unroll
        for (int c = 1; c < 16; ++c) {
            float s2 = redS[row * 17 + c];
            int   i2 = redI[row * 17 + c];
            if (s2 < bs || (s2 == bs && i2 < bi)) { bs = s2; bi = i2; }
        }
        idxOut[row0 + row] = bi;
        const float* cr = cb + (bi << 6);
        float rs = 0.f;
        #pragma unroll
        for (int d = 0; d < 64; ++d) {
            float e = cr[d] - Fs[d * 128 + row];
            rs = fmaf(e, e, rs);
        }
        #pragma unroll
        for (int off = 32; off; off >>= 1) rs += __shfl_down(rs, off, 64);
        if ((t & 63) == 0) atomicAdd(lossAcc, rs);
    }
}

// ---------- d1 via U-table, writes PADDED D1P ----------
__global__ __launch_bounds__(256) void d1p_k(const int* __restrict__ idx,
                                             const float* __restrict__ U,
                                             const float* __restrict__ db1,
                                             float* __restrict__ d1p)
{
    int id = blockIdx.x * 256 + threadIdx.x;       // 262144
    int x = id & 31, y = (id >> 5) & 31;
    int cg = rfl((id >> 10) & 3), n = id >> 12;
    float acc[4];
    #pragma unroll
    for (int j = 0; j < 4; ++j) acc[j] = db1[cg * 4 + j];
    const float4* U4 = (const float4*)U;
    #pragma unroll
    for (int tap = 0; tap < 9; ++tap) {
        int yy = y + tap / 3 - 1, xx = x + tap % 3 - 1;
        if (yy < 0 || yy > 31 || xx < 0 || xx > 31) continue;
        int k = idx[(n << 10) + (yy << 5) + xx];
        float4 u = U4[(k * 9 + tap) * 4 + cg];
        acc[0] += u.x; acc[1] += u.y; acc[2] += u.z; acc[3] += u.w;
    }
    #pragma unroll
    for (int j = 0; j < 4; ++j)
        d1p[((n * 16 + cg * 4 + j) * 34 + y + 1) * 34 + x + 1] = leakyf(acc[j]);
}

// ---------- dt2: ConvT 16->8 K4 S2 P1, parity form, COB2, padded in/out ----
__global__ __launch_bounds__(256) void dt2p_k(const float* __restrict__ d1p,
                                              const float* __restrict__ dw2,
                                              const float* __restrict__ db2,
                                              float* __restrict__ d2p)
{
    __shared__ float wl[512];                      // [ci16][tap16][co2]
    int t = threadIdx.x;
    int id = blockIdx.x * 256 + t;                 // 262144
    int x = id & 31, y = (id >> 5) & 31;
    int cg = rfl((id >> 10) & 3), n = id >> 12;
    for (int i = t; i < 512; i += 256) {
        int co = i & 1, tap = (i >> 1) & 15, ci = i >> 5;
        wl[i] = dw2[(ci * 8 + cg * 2 + co) * 16 + tap];
    }
    __syncthreads();
    float acc[2][2][2];
    #pragma unroll
    for (int py = 0; py < 2; ++py)
        #pragma unroll
        for (int px = 0; px < 2; ++px)
            #pragma unroll
            for (int j = 0; j < 2; ++j) acc[py][px][j] = db2[cg * 2 + j];
    #pragma unroll 1
    for (int ci = 0; ci < 16; ++ci) {
        const float* base = d1p + ((n * 16 + ci) * 34 + y) * 34 + x;
        F4 r0 = *(const F4*)(base);
        F4 r1 = *(const F4*)(base + 34);
        F4 r2 = *(const F4*)(base + 68);
        float v[3][3] = { { r0.x, r0.y, r0.z },
                          { r1.x, r1.y, r1.z },
                          { r2.x, r2.y, r2.z } };
        #pragma unroll
        for (int ky = 0; ky < 4; ++ky) {
            int py = (ky + 1) & 1;
            int dy = (ky == 0) ? 1 : (ky == 3 ? -1 : 0);
            #pragma unroll
            for (int kx = 0; kx < 4; ++kx) {
                int px = (kx + 1) & 1;
                int dx = (kx == 0) ? 1 : (kx == 3 ? -1 : 0);
                float vv = v[dy + 1][dx + 1];
                const float* wp = &wl[(ci * 16 + ky * 4 + kx) * 2];
                acc[py][px][0] = fmaf(vv, wp[0], acc[py][px][0]);
                acc[py][px][1] = fmaf(vv, wp[1], acc[py][px][1]);
            }
        }
    }
    #pragma unroll
    for (int py = 0; py < 2; ++py)
        #pragma unroll
        for (int px = 0; px < 2; ++px)
            #pragma unroll
            for (int j = 0; j < 2; ++j)
                d2p[((n * 8 + cg * 2 + j) * 66 + 2 * y + py + 1) * 66 + 2 * x + px + 1] =
                    leakyf(acc[py][px][j]);
}

// ---------- dt3: ConvT 8->1 K4 S2 P1, parity form, tanh, padded in ----------
__global__ __launch_bounds__(256) void dt3p_k(const float* __restrict__ d2p,
                                              const float* __restrict__ dw3,
                                              const float* __restrict__ db3,
                                              float* __restrict__ out)
{
    int id = blockIdx.x * 256 + threadIdx.x;       // 262144
    int x = id & 63, y = (id >> 6) & 63, n = id >> 12;
    float b = db3[0];
    float acc[2][2] = { { b, b }, { b, b } };
    #pragma unroll 1
    for (int ci = 0; ci < 8; ++ci) {
        const float* base = d2p + ((n * 8 + ci) * 66 + y) * 66 + x;
        F4 r0 = *(const F4*)(base);
        F4 r1 = *(const F4*)(base + 66);
        F4 r2 = *(const F4*)(base + 132);
        float v[3][3] = { { r0.x, r0.y, r0.z },
                          { r1.x, r1.y, r1.z },
                          { r2.x, r2.y, r2.z } };
        #pragma unroll
        for (int ky = 0; ky < 4; ++ky) {
            int py = (ky + 1) & 1;
            int dy = (ky == 0) ? 1 : (ky == 3 ? -1 : 0);
            #pragma unroll
            for (int kx = 0; kx < 4; ++kx) {
                int px = (kx + 1) & 1;
                int dx = (kx == 0) ? 1 : (kx == 3 ? -1 : 0);
                acc[py][px] = fmaf(v[dy + 1][dx + 1], dw3[ci * 16 + ky * 4 + kx],
                                   acc[py][px]);
            }
        }
    }
    #pragma unroll
    for (int py = 0; py < 2; ++py)
        #pragma unroll
        for (int px = 0; px < 2; ++px)
            out[(n << 14) + ((2 * y + py) << 7) + 2 * x + px] = tanhf(acc[py][px]);
}

__global__ void loss_k(const float* __restrict__ acc, float* __restrict__ out)
{
    out[0] = 1.25f * acc[0] / 4194304.0f;
}

extern "C" void kernel_launch(void* const* d_in, const int* in_sizes, int n_in,
                              void* d_out, int out_size, void* d_ws, size_t ws_size,
                              hipStream_t stream)
{
    const float* x        = (const float*)d_in[0];
    const float* ew1      = (const float*)d_in[1];
    const float* eb1      = (const float*)d_in[2];
    const float* ew2      = (const float*)d_in[3];
    const float* eb2      = (const float*)d_in[4];
    const float* ew3      = (const float*)d_in[5];
    const float* eb3      = (const float*)d_in[6];
    const float* ew4      = (const float*)d_in[7];
    const float* eb4      = (const float*)d_in[8];
    const float* codebook = (const float*)d_in[9];
    const float* dw1      = (const float*)d_in[10];
    const float* db1      = (const float*)d_in[11];
    const float* dw2      = (const float*)d_in[12];
    const float* db2      = (const float*)d_in[13];
    const float* dw3      = (const float*)d_in[14];
    const float* db3      = (const float*)d_in[15];

    float* out = (float*)d_out;
    float* ws  = (float*)d_ws;
    float* XP   = ws + OFF_XP;
    float* H1P  = ws + OFF_H1P;
    float* H2P  = ws + OFF_H2P;
    float* H3   = ws + OFF_H3;
    float* D1P  = ws + OFF_D1P;
    float* D2P  = ws + OFF_D2P;
    int*   IDX  = (int*)(ws + OFF_IDX);
    float* U    = ws + OFF_U;
    float* C2   = ws + OFF_C2;
    float* W4T  = ws + OFF_W4T;
    float* DWT  = ws + OFF_DWT;
    float* LOSS = ws + OFF_LOSS;

    hipMemsetAsync(LOSS, 0, sizeof(float), stream);
    prep_k<<<42, 256, 0, stream>>>(ew4, dw1, codebook, ws);
    uprep_k<<<288, 256, 0, stream>>>(DWT, codebook, U);
    halo_k<<<2225, 256, 0, stream>>>(ws);
    padx_k<<<4096, 256, 0, stream>>>(x, XP);

    e1p_k<<<1024, 256, 0, stream>>>(XP, ew1, eb1, H1P);
    e2p_k<<<1024, 256, 0, stream>>>(H1P, ew2, eb2, H2P);
    e3p_k<<<1024, 256, 0, stream>>>(H2P, ew3, eb3, H3);

    vqh_k<<<512, 256, 0, stream>>>(H3, W4T, eb4, codebook, C2, IDX, LOSS);

    d1p_k<<<1024, 256, 0, stream>>>(IDX, U, db1, D1P);
    dt2p_k<<<1024, 256, 0, stream>>>(D1P, dw2, db2, D2P);
    dt3p_k<<<1024, 256, 0, stream>>>(D2P, dw3, db3, out);

    loss_k<<<1, 1, 0, stream>>>(LOSS, out + 1048576);
}